// Round 9
// baseline (2350.021 us; speedup 1.0000x reference)
//
#include <hip/hip_runtime.h>
#include <math.h>

namespace {

constexpr int NATOMS = 1000000;
constexpr int NBATCH = 32768;
constexpr int kCounts[11] = {10000,250000,300000,250000,120000,40000,15000,8000,4000,2000,1000};
constexpr int kStarts[11] = {0,10000,260000,560000,810000,930000,970000,985000,993000,997000,999000};

struct AdjPtrs { const int* p[10]; };

__device__ __forceinline__ unsigned enc_f32(float x) {
    unsigned u = __float_as_uint(x);
    return (u & 0x80000000u) ? ~u : (u | 0x80000000u);
}
__device__ __forceinline__ float dec_f32(unsigned u) {
    return (u & 0x80000000u) ? __uint_as_float(u & 0x7FFFFFFFu) : __uint_as_float(~u);
}

// Bank math: transposed tiles [k][64] have row stride 64 floats = 0 mod 32
// banks -> bank = col&31. Compute-side reads are 4-address 16-way broadcasts
// (conflict-free for any bijective swizzle); staging-write swizzles are derived
// per pattern to land on 32 banks at <=2-way (free):
//  self CI=75 (16 lanes/row scalar): col = row ^ ((k&7)<<2)
//  self CI=64 (16 lanes/row float4): col = row ^ (((k>>2)&7)<<2)
//  rel  8 lanes/atom CI=64 (float4): col = ai  ^ (((k>>2)&3)<<3)
//  rel  8 lanes/atom CI=75 (scalar): col = ai  ^ ((k&3)<<3)
// All swizzle constants avoid bits 0-1 => float2/float4 groups stay contiguous.
__device__ __forceinline__ int swzS75(int row, int k) { return row ^ ((k & 7) << 2); }
__device__ __forceinline__ int swzS64(int row, int k) { return row ^ (((k >> 2) & 7) << 2); }

// ---------------------------------------------------------------------------
// rel-staging bodies (8 lanes per atom; 512-thread blocks)
// ---------------------------------------------------------------------------
template<int D>
__device__ __forceinline__ void stage_rel64_w8(const float* __restrict__ x,
                                               const int* __restrict__ ad,
                                               int j0, int ai, int g8, float (*s_rel)[64])
{
    int idxs[D];
    #pragma unroll
    for (int n = 0; n < D; ++n) idxs[n] = ad[(size_t)(j0 + ai) * D + n];
    float4 r[2];
    r[0] = make_float4(0.f, 0.f, 0.f, 0.f);
    r[1] = make_float4(0.f, 0.f, 0.f, 0.f);
    for (int n = 0; n < D; ++n) {
        const float4* __restrict__ xr = reinterpret_cast<const float4*>(x + (size_t)idxs[n] * 64);
        #pragma unroll
        for (int q = 0; q < 2; ++q) {
            const float4 v = xr[g8 + 8 * q];
            r[q].x += v.x; r[q].y += v.y; r[q].z += v.z; r[q].w += v.w;
        }
    }
    #pragma unroll
    for (int q = 0; q < 2; ++q) {
        const int k0 = (g8 + 8 * q) * 4;
        const int col = ai ^ (((k0 >> 2) & 3) << 3);
        s_rel[k0 + 0][col] = r[q].x;
        s_rel[k0 + 1][col] = r[q].y;
        s_rel[k0 + 2][col] = r[q].z;
        s_rel[k0 + 3][col] = r[q].w;
    }
}

__device__ __forceinline__ void stage_rel64_rt_w8(const float* __restrict__ x,
                                                  const int* __restrict__ ad, int d,
                                                  int j0, int ai, int g8, float (*s_rel)[64])
{
    int idxs[10];
    for (int n = 0; n < d; ++n) idxs[n] = ad[(size_t)(j0 + ai) * d + n];
    float4 r[2];
    r[0] = make_float4(0.f, 0.f, 0.f, 0.f);
    r[1] = make_float4(0.f, 0.f, 0.f, 0.f);
    for (int n = 0; n < d; ++n) {
        const float4* __restrict__ xr = reinterpret_cast<const float4*>(x + (size_t)idxs[n] * 64);
        #pragma unroll
        for (int q = 0; q < 2; ++q) {
            const float4 v = xr[g8 + 8 * q];
            r[q].x += v.x; r[q].y += v.y; r[q].z += v.z; r[q].w += v.w;
        }
    }
    #pragma unroll
    for (int q = 0; q < 2; ++q) {
        const int k0 = (g8 + 8 * q) * 4;
        const int col = ai ^ (((k0 >> 2) & 3) << 3);
        s_rel[k0 + 0][col] = r[q].x;
        s_rel[k0 + 1][col] = r[q].y;
        s_rel[k0 + 2][col] = r[q].z;
        s_rel[k0 + 3][col] = r[q].w;
    }
}

template<int D>
__device__ __forceinline__ void stage_rel75_w8(const float* __restrict__ x,
                                               const int* __restrict__ ad,
                                               int j0, int ai, int g8, float (*s_rel)[64])
{
    int idxs[D];
    #pragma unroll
    for (int n = 0; n < D; ++n) idxs[n] = ad[(size_t)(j0 + ai) * D + n];
    float r[10];
    #pragma unroll
    for (int q = 0; q < 10; ++q) r[q] = 0.f;
    for (int n = 0; n < D; ++n) {
        const float* __restrict__ xr = x + (size_t)idxs[n] * 75;
        #pragma unroll
        for (int q = 0; q < 10; ++q) {
            const int e = g8 + 8 * q;
            if (e < 75) r[q] += xr[e];
        }
    }
    #pragma unroll
    for (int q = 0; q < 10; ++q) {
        const int e = g8 + 8 * q;
        if (e < 75) s_rel[e][ai ^ ((e & 3) << 3)] = r[q];
    }
}

__device__ __forceinline__ void stage_rel75_rt_w8(const float* __restrict__ x,
                                                  const int* __restrict__ ad, int d,
                                                  int j0, int ai, int g8, float (*s_rel)[64])
{
    int idxs[10];
    for (int n = 0; n < d; ++n) idxs[n] = ad[(size_t)(j0 + ai) * d + n];
    float r[10];
    #pragma unroll
    for (int q = 0; q < 10; ++q) r[q] = 0.f;
    for (int n = 0; n < d; ++n) {
        const float* __restrict__ xr = x + (size_t)idxs[n] * 75;
        #pragma unroll
        for (int q = 0; q < 10; ++q) {
            const int e = g8 + 8 * q;
            if (e < 75) r[q] += xr[e];
        }
    }
    #pragma unroll
    for (int q = 0; q < 10; ++q) {
        const int e = g8 + 8 * q;
        if (e < 75) s_rel[e][ai ^ ((e & 3) << 3)] = r[q];
    }
}

// ---------------------------------------------------------------------------
// Merged conv layer: ONE launch, block -> (degree, tile) via count table.
// 512 threads per 64-atom tile (round-8 was 256: LDS 38.4KB capped occupancy
// at 16/32 waves; same LDS with 8 waves/block -> 4 blocks x 8 = 32 waves/CU).
// Micro-tile: 2 atoms x 4 channels per thread.
// ---------------------------------------------------------------------------
template<int CI>
__global__ __launch_bounds__(512, 8) void conv_all_kernel(
    const float* __restrict__ x, AdjPtrs adj,
    const float* __restrict__ W, const float* __restrict__ B,
    const float* __restrict__ bng, const float* __restrict__ bnb,
    const float* __restrict__ bnm, const float* __restrict__ bnv,
    float* __restrict__ out)
{
    __shared__ __align__(16) float s_self[CI][64];
    __shared__ __align__(16) float s_rel[CI][64];

    int d = 0, rem = blockIdx.x;
    for (;;) { const int nb = (kCounts[d] + 63) >> 6; if (rem < nb) break; rem -= nb; ++d; }
    const int j0 = rem << 6;
    const int nA = min(64, kCounts[d] - j0);
    const int a0 = kStarts[d] + j0;
    const int t = threadIdx.x;

    // ---- stage self rows: coalesced global, 2-way LDS banks ----
    if constexpr (CI == 64) {
        for (int v = t; v < 1024; v += 512) {
            const int row = v >> 4, k0 = (v & 15) * 4;
            if (row < nA) {
                const float4 r = *reinterpret_cast<const float4*>(x + (size_t)(a0 + row) * 64 + k0);
                s_self[k0 + 0][swzS64(row, k0 + 0)] = r.x;
                s_self[k0 + 1][swzS64(row, k0 + 1)] = r.y;
                s_self[k0 + 2][swzS64(row, k0 + 2)] = r.z;
                s_self[k0 + 3][swzS64(row, k0 + 3)] = r.w;
            }
        }
    } else {
        for (int v = t; v < 1024; v += 512) {
            const int row = v >> 4, l16 = v & 15;
            if (row < nA) {
                const float* __restrict__ xr = x + (size_t)(a0 + row) * CI;
                #pragma unroll
                for (int q = 0; q < 5; ++q) {
                    const int k = l16 + 16 * q;
                    if (k < CI) s_self[k][swzS75(row, k)] = xr[k];
                }
            }
        }
    }

    // ---- stage neighbor sums (8 lanes/atom) ----
    if (d > 0) {
        const int ai = t >> 3, g8 = t & 7;
        if (ai < nA) {
            const int* __restrict__ ad = adj.p[d - 1];
            if constexpr (CI == 64) {
                switch (d) {
                case 1: stage_rel64_w8<1>(x, ad, j0, ai, g8, s_rel); break;
                case 2: stage_rel64_w8<2>(x, ad, j0, ai, g8, s_rel); break;
                case 3: stage_rel64_w8<3>(x, ad, j0, ai, g8, s_rel); break;
                case 4: stage_rel64_w8<4>(x, ad, j0, ai, g8, s_rel); break;
                default: stage_rel64_rt_w8(x, ad, d, j0, ai, g8, s_rel); break;
                }
            } else {
                switch (d) {
                case 1: stage_rel75_w8<1>(x, ad, j0, ai, g8, s_rel); break;
                case 2: stage_rel75_w8<2>(x, ad, j0, ai, g8, s_rel); break;
                case 3: stage_rel75_w8<3>(x, ad, j0, ai, g8, s_rel); break;
                case 4: stage_rel75_w8<4>(x, ad, j0, ai, g8, s_rel); break;
                default: stage_rel75_rt_w8(x, ad, d, j0, ai, g8, s_rel); break;
                }
            }
        }
    }
    __syncthreads();

    const int c4 = (t & 15) * 4;   // 4 channels
    const int a2 = (t >> 4) * 2;   // 2 atoms

    float acc[2][4];
    #pragma unroll
    for (int i = 0; i < 2; ++i)
        #pragma unroll
        for (int j = 0; j < 4; ++j) acc[i][j] = 0.f;

    if (d == 0) {
        const float* __restrict__ Ws = W + (size_t)(2 * 10) * CI * 64;
        for (int k = 0; k < CI; ++k) {
            const int swS = (CI == 64) ? (((k >> 2) & 7) << 2) : ((k & 7) << 2);
            const float2 sv = *reinterpret_cast<const float2*>(&s_self[k][a2 ^ swS]);
            const float4 ws = *reinterpret_cast<const float4*>(Ws + k * 64 + c4);
            acc[0][0] = fmaf(sv.x, ws.x, acc[0][0]);
            acc[0][1] = fmaf(sv.x, ws.y, acc[0][1]);
            acc[0][2] = fmaf(sv.x, ws.z, acc[0][2]);
            acc[0][3] = fmaf(sv.x, ws.w, acc[0][3]);
            acc[1][0] = fmaf(sv.y, ws.x, acc[1][0]);
            acc[1][1] = fmaf(sv.y, ws.y, acc[1][1]);
            acc[1][2] = fmaf(sv.y, ws.z, acc[1][2]);
            acc[1][3] = fmaf(sv.y, ws.w, acc[1][3]);
        }
    } else {
        const float* __restrict__ Wr = W + (size_t)(2 * (d - 1)) * CI * 64;
        const float* __restrict__ Ws = W + (size_t)(2 * d - 1) * CI * 64;
        for (int k = 0; k < CI; ++k) {
            const int swS = (CI == 64) ? (((k >> 2) & 7) << 2) : ((k & 7) << 2);
            const int swR = (CI == 64) ? (((k >> 2) & 3) << 3) : ((k & 3) << 3);
            const float2 sv = *reinterpret_cast<const float2*>(&s_self[k][a2 ^ swS]);
            const float2 rv = *reinterpret_cast<const float2*>(&s_rel [k][a2 ^ swR]);
            const float4 ws = *reinterpret_cast<const float4*>(Ws + k * 64 + c4);
            const float4 wr = *reinterpret_cast<const float4*>(Wr + k * 64 + c4);
            acc[0][0] = fmaf(sv.x, ws.x, fmaf(rv.x, wr.x, acc[0][0]));
            acc[0][1] = fmaf(sv.x, ws.y, fmaf(rv.x, wr.y, acc[0][1]));
            acc[0][2] = fmaf(sv.x, ws.z, fmaf(rv.x, wr.z, acc[0][2]));
            acc[0][3] = fmaf(sv.x, ws.w, fmaf(rv.x, wr.w, acc[0][3]));
            acc[1][0] = fmaf(sv.y, ws.x, fmaf(rv.y, wr.x, acc[1][0]));
            acc[1][1] = fmaf(sv.y, ws.y, fmaf(rv.y, wr.y, acc[1][1]));
            acc[1][2] = fmaf(sv.y, ws.z, fmaf(rv.y, wr.z, acc[1][2]));
            acc[1][3] = fmaf(sv.y, ws.w, fmaf(rv.y, wr.w, acc[1][3]));
        }
    }

    // epilogue: bias + ReLU + folded BN (per 4 channels), float4 stores
    float4 bia;
    if (d == 0) {
        bia = *reinterpret_cast<const float4*>(B + 20 * 64 + c4);
    } else {
        const float4 b1 = *reinterpret_cast<const float4*>(B + (2 * (d - 1)) * 64 + c4);
        const float4 b2 = *reinterpret_cast<const float4*>(B + (2 * d - 1) * 64 + c4);
        bia = make_float4(b1.x + b2.x, b1.y + b2.y, b1.z + b2.z, b1.w + b2.w);
    }
    const float4 gg = *reinterpret_cast<const float4*>(bng + c4);
    const float4 be = *reinterpret_cast<const float4*>(bnb + c4);
    const float4 mm = *reinterpret_cast<const float4*>(bnm + c4);
    const float4 vv = *reinterpret_cast<const float4*>(bnv + c4);
    float sc[4], sh[4];
    sc[0] = rsqrtf(vv.x + 1e-3f) * gg.x; sh[0] = be.x - mm.x * sc[0];
    sc[1] = rsqrtf(vv.y + 1e-3f) * gg.y; sh[1] = be.y - mm.y * sc[1];
    sc[2] = rsqrtf(vv.z + 1e-3f) * gg.z; sh[2] = be.z - mm.z * sc[2];
    sc[3] = rsqrtf(vv.w + 1e-3f) * gg.w; sh[3] = be.w - mm.w * sc[3];
    const float bi[4] = {bia.x, bia.y, bia.z, bia.w};

    #pragma unroll
    for (int i = 0; i < 2; ++i) {
        const int ai = a2 + i;
        if (ai < nA) {
            float4 o;
            o.x = fmaf(fmaxf(acc[i][0] + bi[0], 0.f), sc[0], sh[0]);
            o.y = fmaf(fmaxf(acc[i][1] + bi[1], 0.f), sc[1], sh[1]);
            o.z = fmaf(fmaxf(acc[i][2] + bi[2], 0.f), sc[2], sh[2]);
            o.w = fmaf(fmaxf(acc[i][3] + bi[3], 0.f), sc[3], sh[3]);
            *reinterpret_cast<float4*>(out + (size_t)(a0 + ai) * 64 + c4) = o;
        }
    }
}

// ---------------------------------------------------------------------------
// Merged pool layer: ONE launch; 4 atoms per block (one wave each, lane=ch).
// ---------------------------------------------------------------------------
template<int D>
__device__ __forceinline__ float pool_body(const float* __restrict__ z,
                                           const int* __restrict__ ad, int j, int c, float v)
{
    int idxs[D];
    #pragma unroll
    for (int n = 0; n < D; ++n) idxs[n] = ad[(size_t)j * D + n];
    #pragma unroll
    for (int n = 0; n < D; ++n) v = fmaxf(v, z[(size_t)idxs[n] * 64 + c]);
    return v;
}

__global__ __launch_bounds__(256) void pool_all_kernel(
    const float* __restrict__ z, AdjPtrs adj, float* __restrict__ p)
{
    int d = 0, rem = blockIdx.x;
    for (;;) { const int nb = (kCounts[d] + 3) >> 2; if (rem < nb) break; rem -= nb; ++d; }
    const int t = threadIdx.x;
    const int j = rem * 4 + (t >> 6);
    if (j >= kCounts[d]) return;
    const int c = t & 63;
    const int a = kStarts[d] + j;
    float v = z[(size_t)a * 64 + c];
    if (d > 0) {
        const int* __restrict__ ad = adj.p[d - 1];
        switch (d) {
        case 1:  v = pool_body<1 >(z, ad, j, c, v); break;
        case 2:  v = pool_body<2 >(z, ad, j, c, v); break;
        case 3:  v = pool_body<3 >(z, ad, j, c, v); break;
        case 4:  v = pool_body<4 >(z, ad, j, c, v); break;
        case 5:  v = pool_body<5 >(z, ad, j, c, v); break;
        case 6:  v = pool_body<6 >(z, ad, j, c, v); break;
        case 7:  v = pool_body<7 >(z, ad, j, c, v); break;
        case 8:  v = pool_body<8 >(z, ad, j, c, v); break;
        case 9:  v = pool_body<9 >(z, ad, j, c, v); break;
        default: v = pool_body<10>(z, ad, j, c, v); break;
        }
    }
    p[(size_t)a * 64 + c] = v;
}

// ---------------------------------------------------------------------------
// Counting sort by membership: hist -> scan -> scatter (+ per-position seg id).
// ---------------------------------------------------------------------------
__global__ __launch_bounds__(256) void hist_kernel(const int* __restrict__ mem,
                                                   int* __restrict__ cnt)
{
    const int a = blockIdx.x * 256 + threadIdx.x;
    if (a < NATOMS) atomicAdd(&cnt[mem[a]], 1);
}

__global__ __launch_bounds__(512) void scan_kernel(const int* __restrict__ cnt,
                                                   int* __restrict__ off,
                                                   int* __restrict__ cur)
{
    __shared__ int part[512];
    const int t = threadIdx.x;
    const int base = t * 64;
    int s = 0;
    #pragma unroll 8
    for (int i = 0; i < 64; ++i) s += cnt[base + i];
    part[t] = s;
    __syncthreads();
    for (int o = 1; o < 512; o <<= 1) {
        int v = (t >= o) ? part[t - o] : 0;
        __syncthreads();
        part[t] += v;
        __syncthreads();
    }
    int run = (t == 0) ? 0 : part[t - 1];
    for (int i = 0; i < 64; ++i) {
        off[base + i] = run;
        cur[base + i] = run;
        run += cnt[base + i];
    }
}

__global__ __launch_bounds__(256) void scatter_kernel(const int* __restrict__ mem,
                                                      int* __restrict__ cur,
                                                      int* __restrict__ sorted,
                                                      int* __restrict__ sid)
{
    const int a = blockIdx.x * 256 + threadIdx.x;
    if (a < NATOMS) {
        const int m = mem[a];
        const int pos = atomicAdd(&cur[m], 1);
        sorted[pos] = a;
        sid[pos] = m;
    }
}

__global__ void seg_init_kernel(float* __restrict__ segS, unsigned* __restrict__ segM)
{
    const int n = NBATCH * 128;
    for (int i = blockIdx.x * blockDim.x + threadIdx.x; i < n; i += gridDim.x * blockDim.x) {
        segS[i] = 0.f;
        segM[i] = 0x007FFFFFu; // enc(-inf)
    }
}

// ---------------------------------------------------------------------------
// Dense 64->128 + ReLU + BN2 over SORTED atoms (tiled GEMM, 64 rows x 128 ch
// per block) with fused segmented sum/max epilogue. LDS ~17KB -> 8 blocks/CU.
// ---------------------------------------------------------------------------
__global__ __launch_bounds__(256) void dense_seg_sorted_kernel(
    const float* __restrict__ p,
    const int* __restrict__ sorted, const int* __restrict__ sid,
    const float* __restrict__ Wd, const float* __restrict__ bd,
    const float* __restrict__ bng, const float* __restrict__ bnb,
    const float* __restrict__ bnm, const float* __restrict__ bnv,
    float* __restrict__ segS, unsigned* __restrict__ segM)
{
    __shared__ __align__(16) float s_p[64][64];   // staging; reused as v-buffer
    __shared__ int s_idx[64];
    __shared__ int s_sid[64];

    const int t = threadIdx.x;
    const int pos0 = blockIdx.x * 64;   // NATOMS = 15625 * 64 exactly

    if (t < 64) {
        s_idx[t] = sorted[pos0 + t];
        s_sid[t] = sid[pos0 + t];
    }
    __syncthreads();

    for (int v = t; v < 1024; v += 256) {
        const int row = v >> 4, k0 = (v & 15) * 4;
        const float4 r = *reinterpret_cast<const float4*>(p + (size_t)s_idx[row] * 64 + k0);
        s_p[k0 + 0][swzS64(row, k0 + 0)] = r.x;
        s_p[k0 + 1][swzS64(row, k0 + 1)] = r.y;
        s_p[k0 + 2][swzS64(row, k0 + 2)] = r.z;
        s_p[k0 + 3][swzS64(row, k0 + 3)] = r.w;
    }
    __syncthreads();

    const int ccol = (t & 31) * 4;   // 4 consecutive output channels
    const int rgrp = t >> 5;         // 8 rows: rgrp*8 .. rgrp*8+7

    float acc[8][4];
    #pragma unroll
    for (int i = 0; i < 8; ++i)
        #pragma unroll
        for (int j = 0; j < 4; ++j) acc[i][j] = 0.f;

    for (int k = 0; k < 64; ++k) {
        const float4 w = *reinterpret_cast<const float4*>(Wd + (size_t)k * 128 + ccol);
        const int sw = ((k >> 2) & 7) << 2;
        #pragma unroll
        for (int h = 0; h < 2; ++h) {
            const float4 rv = *reinterpret_cast<const float4*>(&s_p[k][(rgrp * 8 + h * 4) ^ sw]);
            const float rr[4] = {rv.x, rv.y, rv.z, rv.w};
            #pragma unroll
            for (int j = 0; j < 4; ++j) {
                acc[h*4+j][0] = fmaf(rr[j], w.x, acc[h*4+j][0]);
                acc[h*4+j][1] = fmaf(rr[j], w.y, acc[h*4+j][1]);
                acc[h*4+j][2] = fmaf(rr[j], w.z, acc[h*4+j][2]);
                acc[h*4+j][3] = fmaf(rr[j], w.w, acc[h*4+j][3]);
            }
        }
    }

    {
        const float4 bb = *reinterpret_cast<const float4*>(bd + ccol);
        const float4 gg = *reinterpret_cast<const float4*>(bng + ccol);
        const float4 be = *reinterpret_cast<const float4*>(bnb + ccol);
        const float4 mm = *reinterpret_cast<const float4*>(bnm + ccol);
        const float4 vv = *reinterpret_cast<const float4*>(bnv + ccol);
        const float bia[4] = {bb.x, bb.y, bb.z, bb.w};
        float sc[4], sh[4];
        sc[0] = rsqrtf(vv.x + 1e-3f) * gg.x; sh[0] = be.x - mm.x * sc[0];
        sc[1] = rsqrtf(vv.y + 1e-3f) * gg.y; sh[1] = be.y - mm.y * sc[1];
        sc[2] = rsqrtf(vv.z + 1e-3f) * gg.z; sh[2] = be.z - mm.z * sc[2];
        sc[3] = rsqrtf(vv.w + 1e-3f) * gg.w; sh[3] = be.w - mm.w * sc[3];
        #pragma unroll
        for (int i = 0; i < 8; ++i)
            #pragma unroll
            for (int j = 0; j < 4; ++j)
                acc[i][j] = fmaf(fmaxf(acc[i][j] + bia[j], 0.f), sc[j], sh[j]);
    }

    __syncthreads();   // all GEMM reads of s_p complete -> safe to overwrite

    float (*vbuf)[64] = s_p;
    const int halfSel = ccol >> 6;
    const int cc = ccol & 63;

    #pragma unroll
    for (int half = 0; half < 2; ++half) {
        if (halfSel == half) {
            #pragma unroll
            for (int i = 0; i < 8; ++i) {
                float4 o = make_float4(acc[i][0], acc[i][1], acc[i][2], acc[i][3]);
                *reinterpret_cast<float4*>(&vbuf[rgrp * 8 + i][cc]) = o;
            }
        }
        __syncthreads();

        const int c = t & 63;
        const int rbase = (t >> 6) * 16;
        const int gch = half * 64 + c;
        int cur = s_sid[rbase];
        float s = 0.f, mx = -INFINITY;
        for (int r = rbase; r < rbase + 16; ++r) {
            const int sd = s_sid[r];
            if (sd != cur) {
                atomicAdd(&segS[(size_t)cur * 128 + gch], s);
                atomicMax(&segM[(size_t)cur * 128 + gch], enc_f32(mx));
                cur = sd; s = 0.f; mx = -INFINITY;
            }
            const float v = vbuf[r][c];
            s += v;
            mx = fmaxf(mx, v);
        }
        atomicAdd(&segS[(size_t)cur * 128 + gch], s);
        atomicMax(&segM[(size_t)cur * 128 + gch], enc_f32(mx));
        __syncthreads();
    }
}

__global__ void nf_fin_kernel(const float* __restrict__ segS,
                              const unsigned* __restrict__ segM,
                              float* __restrict__ nf)
{
    const int i = blockIdx.x * blockDim.x + threadIdx.x; // < NBATCH*128
    const int m = i >> 7, c = i & 127;
    nf[(size_t)m * 256 + c]       = tanhf(segS[i]);
    nf[(size_t)m * 256 + 128 + c] = tanhf(dec_f32(segM[i]));
}

// fd0: h = relu(nf @ W + b), 32768x256 @ 256x256. 64x64 tile per block.
// 4x4 micro-tile compute.
__global__ __launch_bounds__(256) void fd0_kernel(
    const float* __restrict__ nf, const float* __restrict__ W, const float* __restrict__ b,
    float* __restrict__ h)
{
    __shared__ __align__(16) float sx[256][64];
    const int t = threadIdx.x;
    const int r0 = (blockIdx.x >> 2) * 64;
    const int c0 = (blockIdx.x & 3) * 64;
    for (int ch = 0; ch < 4; ++ch) {
        for (int v = t; v < 1024; v += 256) {
            const int row = v >> 4, k0 = (v & 15) * 4 + ch * 64;
            const float4 r = *reinterpret_cast<const float4*>(nf + (size_t)(r0 + row) * 256 + k0);
            sx[k0 + 0][swzS64(row, k0 + 0)] = r.x;
            sx[k0 + 1][swzS64(row, k0 + 1)] = r.y;
            sx[k0 + 2][swzS64(row, k0 + 2)] = r.z;
            sx[k0 + 3][swzS64(row, k0 + 3)] = r.w;
        }
    }
    __syncthreads();

    const int c4 = (t & 15) * 4;
    const int a4 = (t >> 4) * 4;

    float acc[4][4];
    #pragma unroll
    for (int i = 0; i < 4; ++i)
        #pragma unroll
        for (int j = 0; j < 4; ++j) acc[i][j] = 0.f;

    for (int k = 0; k < 256; ++k) {
        const int sw = ((k >> 2) & 7) << 2;
        const float4 sv = *reinterpret_cast<const float4*>(&sx[k][a4 ^ sw]);
        const float4 w = *reinterpret_cast<const float4*>(W + (size_t)k * 256 + c0 + c4);
        const float ss[4] = {sv.x, sv.y, sv.z, sv.w};
        #pragma unroll
        for (int i = 0; i < 4; ++i) {
            acc[i][0] = fmaf(ss[i], w.x, acc[i][0]);
            acc[i][1] = fmaf(ss[i], w.y, acc[i][1]);
            acc[i][2] = fmaf(ss[i], w.z, acc[i][2]);
            acc[i][3] = fmaf(ss[i], w.w, acc[i][3]);
        }
    }

    const float4 bb = *reinterpret_cast<const float4*>(b + c0 + c4);
    const float bi[4] = {bb.x, bb.y, bb.z, bb.w};
    #pragma unroll
    for (int i = 0; i < 4; ++i) {
        float4 o;
        o.x = fmaxf(acc[i][0] + bi[0], 0.f);
        o.y = fmaxf(acc[i][1] + bi[1], 0.f);
        o.z = fmaxf(acc[i][2] + bi[2], 0.f);
        o.w = fmaxf(acc[i][3] + bi[3], 0.f);
        *reinterpret_cast<float4*>(h + (size_t)(r0 + a4 + i) * 256 + c0 + c4) = o;
    }
}

// rd: logits = h @ W + b (256->24), then pairwise softmax.
__global__ __launch_bounds__(384) void rd_kernel(
    const float* __restrict__ h, const float* __restrict__ W, const float* __restrict__ b,
    float* __restrict__ outP, float* __restrict__ outL)
{
    __shared__ float sh[32][257];
    const int t = threadIdx.x;
    const int r0 = blockIdx.x * 32;
    for (int e = t; e < 32 * 256; e += 384) {
        const int ri = e >> 8, k = e & 255;
        sh[ri][k] = h[(size_t)(r0 + ri) * 256 + k];
    }
    __syncthreads();
    const int r = t / 12, pj = t % 12;
    float a0 = b[2 * pj], a1 = b[2 * pj + 1];
    for (int k = 0; k < 256; ++k) {
        const float hv = sh[r][k];
        a0 = fmaf(hv, W[k * 24 + 2 * pj],     a0);
        a1 = fmaf(hv, W[k * 24 + 2 * pj + 1], a1);
    }
    const size_t m = (size_t)(r0 + r);
    outL[m * 24 + 2 * pj]     = a0;
    outL[m * 24 + 2 * pj + 1] = a1;
    const float mx = fmaxf(a0, a1);
    const float e0 = expf(a0 - mx), e1 = expf(a1 - mx);
    const float inv = 1.f / (e0 + e1);
    outP[m * 24 + 2 * pj]     = e0 * inv;
    outP[m * 24 + 2 * pj + 1] = e1 * inv;
}

} // namespace

extern "C" void kernel_launch(void* const* d_in, const int* in_sizes, int n_in,
                              void* d_out, int out_size, void* d_ws, size_t ws_size,
                              hipStream_t stream)
{
    const float* x       = (const float*)d_in[0];
    const int*   mem     = (const int*)d_in[2];
    AdjPtrs adj;
    for (int d = 0; d < 10; ++d) adj.p[d] = (const int*)d_in[4 + d];
    const float* gc0_W = (const float*)d_in[14];
    const float* gc0_b = (const float*)d_in[15];
    const float* gc1_W = (const float*)d_in[16];
    const float* gc1_b = (const float*)d_in[17];
    const float* bn0g = (const float*)d_in[18], *bn0b = (const float*)d_in[19];
    const float* bn0m = (const float*)d_in[20], *bn0v = (const float*)d_in[21];
    const float* bn1g = (const float*)d_in[22], *bn1b = (const float*)d_in[23];
    const float* bn1m = (const float*)d_in[24], *bn1v = (const float*)d_in[25];
    const float* bn2g = (const float*)d_in[26], *bn2b = (const float*)d_in[27];
    const float* bn2m = (const float*)d_in[28], *bn2v = (const float*)d_in[29];
    const float* dW   = (const float*)d_in[30], *db   = (const float*)d_in[31];
    const float* fW   = (const float*)d_in[32], *fb   = (const float*)d_in[33];
    const float* rW   = (const float*)d_in[34], *rb   = (const float*)d_in[35];

    float*    zbuf = (float*)d_ws;
    float*    pbuf = zbuf + (size_t)NATOMS * 64;
    float*    hbuf = pbuf + (size_t)NATOMS * 64;
    float*    segS = hbuf + (size_t)NBATCH * 256;
    unsigned* segM = (unsigned*)(segS + (size_t)NBATCH * 128);
    int*      cnt    = (int*)(segM + (size_t)NBATCH * 128);
    int*      offp   = cnt + NBATCH;
    int*      cur    = offp + NBATCH;
    int*      sorted = cur + NBATCH;
    int*      sid    = sorted + NATOMS;

    float* outP = (float*)d_out;
    float* outL = outP + (size_t)NBATCH * 24;
    float* nfb  = outL + (size_t)NBATCH * 24;

    int convBlocks = 0, poolBlocks = 0;
    for (int d = 0; d <= 10; ++d) {
        convBlocks += (kCounts[d] + 63) >> 6;
        poolBlocks += (kCounts[d] + 3) >> 2;
    }

    // counting sort by membership + segment accumulator init
    hipMemsetAsync(cnt, 0, NBATCH * sizeof(int), stream);
    hist_kernel<<<(NATOMS + 255) / 256, 256, 0, stream>>>(mem, cnt);
    scan_kernel<<<1, 512, 0, stream>>>(cnt, offp, cur);
    scatter_kernel<<<(NATOMS + 255) / 256, 256, 0, stream>>>(mem, cur, sorted, sid);
    seg_init_kernel<<<2048, 256, 0, stream>>>(segS, segM);

    // layer 1: conv(75->64)+relu+bn0 -> pool   (one launch each)
    conv_all_kernel<75><<<convBlocks, 512, 0, stream>>>(x, adj, gc0_W, gc0_b,
                                                        bn0g, bn0b, bn0m, bn0v, zbuf);
    pool_all_kernel<<<poolBlocks, 256, 0, stream>>>(zbuf, adj, pbuf);

    // layer 2: conv(64->64)+relu+bn1 -> pool
    conv_all_kernel<64><<<convBlocks, 512, 0, stream>>>(pbuf, adj, gc1_W, gc1_b,
                                                        bn1g, bn1b, bn1m, bn1v, zbuf);
    pool_all_kernel<<<poolBlocks, 256, 0, stream>>>(zbuf, adj, pbuf);

    // dense+relu+bn2 over sorted atoms with fused segmented sum/max
    dense_seg_sorted_kernel<<<NATOMS / 64, 256, 0, stream>>>(
        pbuf, sorted, sid, dW, db, bn2g, bn2b, bn2m, bn2v, segS, segM);
    // nf = tanh(concat(sum, max))
    nf_fin_kernel<<<(NBATCH * 128) / 256, 256, 0, stream>>>(segS, segM, nfb);
    // h = relu(nf @ fd0_W + fd0_b)
    fd0_kernel<<<(NBATCH / 64) * 4, 256, 0, stream>>>(nfb, fW, fb, hbuf);
    // logits + softmax
    rd_kernel<<<NBATCH / 32, 384, 0, stream>>>(hbuf, rW, rb, outP, outL);
}

// Round 10
// 1907.832 us; speedup vs baseline: 1.2318x; 1.2318x over previous
//
#include <hip/hip_runtime.h>
#include <math.h>

namespace {

constexpr int NATOMS = 1000000;
constexpr int NBATCH = 32768;
constexpr int kCounts[11] = {10000,250000,300000,250000,120000,40000,15000,8000,4000,2000,1000};
constexpr int kStarts[11] = {0,10000,260000,560000,810000,930000,970000,985000,993000,997000,999000};

struct AdjPtrs { const int* p[10]; };

__device__ __forceinline__ unsigned enc_f32(float x) {
    unsigned u = __float_as_uint(x);
    return (u & 0x80000000u) ? ~u : (u | 0x80000000u);
}
__device__ __forceinline__ float dec_f32(unsigned u) {
    return (u & 0x80000000u) ? __uint_as_float(u & 0x7FFFFFFFu) : __uint_as_float(~u);
}

// Bank math: transposed tiles [k][64] have row stride 64 floats = 0 mod 32
// banks -> bank = col&31. Staging-write swizzles give 32 banks <=2-way (free);
// compute-side per-lane ds_read_b32 of a bijective permutation of 0..63 is
// also 2-way (free).
__device__ __forceinline__ int swzS75(int row, int k) { return row ^ ((k & 7) << 2); }
__device__ __forceinline__ int swzS64(int row, int k) { return row ^ (((k >> 2) & 7) << 2); }
__device__ __forceinline__ int swzRel(int ai, int k)  { return ai ^ ((k & 15) << 2); }

// ---------------------------------------------------------------------------
// rel-staging bodies (4 lanes per atom; 256-thread blocks)  [round-8 proven]
// ---------------------------------------------------------------------------
template<int D>
__device__ __forceinline__ void stage_rel64(const float* __restrict__ x,
                                            const int* __restrict__ ad,
                                            int j0, int ai, int g4, float (*s_rel)[64])
{
    int idxs[D];
    #pragma unroll
    for (int n = 0; n < D; ++n) idxs[n] = ad[(size_t)(j0 + ai) * D + n];
    float4 r[4];
    #pragma unroll
    for (int q = 0; q < 4; ++q) r[q] = make_float4(0.f, 0.f, 0.f, 0.f);
    for (int n = 0; n < D; ++n) {
        const float4* __restrict__ xr = reinterpret_cast<const float4*>(x + (size_t)idxs[n] * 64);
        #pragma unroll
        for (int q = 0; q < 4; ++q) {
            const float4 v = xr[g4 + 4 * q];
            r[q].x += v.x; r[q].y += v.y; r[q].z += v.z; r[q].w += v.w;
        }
    }
    #pragma unroll
    for (int q = 0; q < 4; ++q) {
        const int k0 = (g4 + 4 * q) * 4;
        s_rel[k0 + 0][swzRel(ai, k0 + 0)] = r[q].x;
        s_rel[k0 + 1][swzRel(ai, k0 + 1)] = r[q].y;
        s_rel[k0 + 2][swzRel(ai, k0 + 2)] = r[q].z;
        s_rel[k0 + 3][swzRel(ai, k0 + 3)] = r[q].w;
    }
}

__device__ __forceinline__ void stage_rel64_rt(const float* __restrict__ x,
                                               const int* __restrict__ ad, int d,
                                               int j0, int ai, int g4, float (*s_rel)[64])
{
    int idxs[10];
    for (int n = 0; n < d; ++n) idxs[n] = ad[(size_t)(j0 + ai) * d + n];
    float4 r[4];
    #pragma unroll
    for (int q = 0; q < 4; ++q) r[q] = make_float4(0.f, 0.f, 0.f, 0.f);
    for (int n = 0; n < d; ++n) {
        const float4* __restrict__ xr = reinterpret_cast<const float4*>(x + (size_t)idxs[n] * 64);
        #pragma unroll
        for (int q = 0; q < 4; ++q) {
            const float4 v = xr[g4 + 4 * q];
            r[q].x += v.x; r[q].y += v.y; r[q].z += v.z; r[q].w += v.w;
        }
    }
    #pragma unroll
    for (int q = 0; q < 4; ++q) {
        const int k0 = (g4 + 4 * q) * 4;
        s_rel[k0 + 0][swzRel(ai, k0 + 0)] = r[q].x;
        s_rel[k0 + 1][swzRel(ai, k0 + 1)] = r[q].y;
        s_rel[k0 + 2][swzRel(ai, k0 + 2)] = r[q].z;
        s_rel[k0 + 3][swzRel(ai, k0 + 3)] = r[q].w;
    }
}

template<int D>
__device__ __forceinline__ void stage_rel75(const float* __restrict__ x,
                                            const int* __restrict__ ad,
                                            int j0, int ai, int g4, float (*s_rel)[64])
{
    int idxs[D];
    #pragma unroll
    for (int n = 0; n < D; ++n) idxs[n] = ad[(size_t)(j0 + ai) * D + n];
    float r[19];
    #pragma unroll
    for (int q = 0; q < 19; ++q) r[q] = 0.f;
    for (int n = 0; n < D; ++n) {
        const float* __restrict__ xr = x + (size_t)idxs[n] * 75;
        #pragma unroll
        for (int q = 0; q < 19; ++q) {
            const int e = g4 + 4 * q;
            if (e < 75) r[q] += xr[e];
        }
    }
    #pragma unroll
    for (int q = 0; q < 19; ++q) {
        const int e = g4 + 4 * q;
        if (e < 75) s_rel[e][swzRel(ai, e)] = r[q];
    }
}

__device__ __forceinline__ void stage_rel75_rt(const float* __restrict__ x,
                                               const int* __restrict__ ad, int d,
                                               int j0, int ai, int g4, float (*s_rel)[64])
{
    int idxs[10];
    for (int n = 0; n < d; ++n) idxs[n] = ad[(size_t)(j0 + ai) * d + n];
    float r[19];
    #pragma unroll
    for (int q = 0; q < 19; ++q) r[q] = 0.f;
    for (int n = 0; n < d; ++n) {
        const float* __restrict__ xr = x + (size_t)idxs[n] * 75;
        #pragma unroll
        for (int q = 0; q < 19; ++q) {
            const int e = g4 + 4 * q;
            if (e < 75) r[q] += xr[e];
        }
    }
    #pragma unroll
    for (int q = 0; q < 19; ++q) {
        const int e = g4 + 4 * q;
        if (e < 75) s_rel[e][swzRel(ai, e)] = r[q];
    }
}

// ---------------------------------------------------------------------------
// Merged conv layer: ONE launch, block -> (degree, tile) via count table.
// 256 threads per 64-atom tile.
// Compute map: atom-per-lane (a = t&63), channel group c0 = readfirstlane(t>>6)*16
// -> ALL weight/bias/BN addresses are wave-uniform -> s_load (SMEM/constant
// cache), ZERO per-k VMEM. Rounds 7-9 showed a ~310-520us stall invariant to
// compute efficiency: per-k float4 weight loads thrashed the 32KB L1 (working
// set 33-38KB x multiple degrees per CU) exposing L2 latency each iteration.
// Stores go through a rotated LDS buffer (vout[64][65]) for coalescing.
// ---------------------------------------------------------------------------
template<int CI>
__global__ __launch_bounds__(256) void conv_all_kernel(
    const float* __restrict__ x, AdjPtrs adj,
    const float* __restrict__ W, const float* __restrict__ B,
    const float* __restrict__ bng, const float* __restrict__ bnb,
    const float* __restrict__ bnm, const float* __restrict__ bnv,
    float* __restrict__ out)
{
    __shared__ __align__(16) float smem[2 * CI * 64];
    float* s_self = smem;                 // [CI][64] transposed+swizzled
    float (*s_rel)[64] = reinterpret_cast<float(*)[64]>(smem + CI * 64);

    int d = 0, rem = blockIdx.x;
    for (;;) { const int nb = (kCounts[d] + 63) >> 6; if (rem < nb) break; rem -= nb; ++d; }
    const int j0 = rem << 6;
    const int nA = min(64, kCounts[d] - j0);
    const int a0 = kStarts[d] + j0;
    const int t = threadIdx.x;

    // ---- stage self rows: coalesced global, 2-way LDS banks ----
    if constexpr (CI == 64) {
        for (int v = t; v < 1024; v += 256) {
            const int row = v >> 4, k0 = (v & 15) * 4;
            if (row < nA) {
                const float4 r = *reinterpret_cast<const float4*>(x + (size_t)(a0 + row) * 64 + k0);
                s_self[(k0 + 0) * 64 + swzS64(row, k0 + 0)] = r.x;
                s_self[(k0 + 1) * 64 + swzS64(row, k0 + 1)] = r.y;
                s_self[(k0 + 2) * 64 + swzS64(row, k0 + 2)] = r.z;
                s_self[(k0 + 3) * 64 + swzS64(row, k0 + 3)] = r.w;
            }
        }
    } else {
        for (int v = t; v < 1024; v += 256) {
            const int row = v >> 4, l16 = v & 15;
            if (row < nA) {
                const float* __restrict__ xr = x + (size_t)(a0 + row) * CI;
                #pragma unroll
                for (int q = 0; q < 5; ++q) {
                    const int k = l16 + 16 * q;
                    if (k < CI) s_self[k * 64 + swzS75(row, k)] = xr[k];
                }
            }
        }
    }

    // ---- stage neighbor sums (4 lanes/atom) ----
    if (d > 0) {
        const int ai = t >> 2, g4 = t & 3;
        if (ai < nA) {
            const int* __restrict__ ad = adj.p[d - 1];
            if constexpr (CI == 64) {
                switch (d) {
                case 1: stage_rel64<1>(x, ad, j0, ai, g4, s_rel); break;
                case 2: stage_rel64<2>(x, ad, j0, ai, g4, s_rel); break;
                case 3: stage_rel64<3>(x, ad, j0, ai, g4, s_rel); break;
                case 4: stage_rel64<4>(x, ad, j0, ai, g4, s_rel); break;
                default: stage_rel64_rt(x, ad, d, j0, ai, g4, s_rel); break;
                }
            } else {
                switch (d) {
                case 1: stage_rel75<1>(x, ad, j0, ai, g4, s_rel); break;
                case 2: stage_rel75<2>(x, ad, j0, ai, g4, s_rel); break;
                case 3: stage_rel75<3>(x, ad, j0, ai, g4, s_rel); break;
                case 4: stage_rel75<4>(x, ad, j0, ai, g4, s_rel); break;
                default: stage_rel75_rt(x, ad, d, j0, ai, g4, s_rel); break;
                }
            }
        }
    }
    __syncthreads();

    // ---- compute: atom-per-lane, 16 channels/thread, scalar weights ----
    const int a  = t & 63;
    const int c0 = __builtin_amdgcn_readfirstlane(t >> 6) * 16;   // wave-uniform

    float acc[16];
    #pragma unroll
    for (int j = 0; j < 16; ++j) acc[j] = 0.f;

    if (d == 0) {
        const float* __restrict__ Ws = W + (size_t)(2 * 10) * CI * 64;
        #pragma unroll
        for (int k = 0; k < CI; ++k) {
            const int swS = (CI == 64) ? (((k >> 2) & 7) << 2) : ((k & 7) << 2);
            const float xs = s_self[k * 64 + (a ^ swS)];
            #pragma unroll
            for (int j = 0; j < 16; ++j)
                acc[j] = fmaf(xs, Ws[k * 64 + c0 + j], acc[j]);
        }
    } else {
        const float* __restrict__ Wr = W + (size_t)(2 * (d - 1)) * CI * 64;
        const float* __restrict__ Ws = W + (size_t)(2 * d - 1) * CI * 64;
        #pragma unroll
        for (int k = 0; k < CI; ++k) {
            const int swS = (CI == 64) ? (((k >> 2) & 7) << 2) : ((k & 7) << 2);
            const int swR = (k & 15) << 2;
            const float xs = s_self[k * 64 + (a ^ swS)];
            const float xr = s_rel[k][a ^ swR];
            #pragma unroll
            for (int j = 0; j < 16; ++j)
                acc[j] = fmaf(xs, Ws[k * 64 + c0 + j],
                              fmaf(xr, Wr[k * 64 + c0 + j], acc[j]));
        }
    }

    // ---- epilogue: scalar bias/BN, rotated-LDS transpose, coalesced store --
    __syncthreads();          // all LDS reads done -> safe to overwrite smem
    float* vout = smem;       // [64][65] rotated buffer (4160 floats <= 8192)
    #pragma unroll
    for (int j = 0; j < 16; ++j) {
        const int c = c0 + j;                               // wave-uniform
        const float bias = (d == 0) ? B[20 * 64 + c]
                                    : (B[(2 * (d - 1)) * 64 + c] + B[(2 * d - 1) * 64 + c]);
        const float scl = rsqrtf(bnv[c] + 1e-3f) * bng[c];
        const float sht = bnb[c] - bnm[c] * scl;
        vout[a * 65 + c] = fmaf(fmaxf(acc[j] + bias, 0.f), scl, sht);
    }
    __syncthreads();
    const int cc = t & 63, g = t >> 6;
    #pragma unroll
    for (int i = 0; i < 16; ++i) {
        const int row = g * 16 + i;
        if (row < nA) out[(size_t)(a0 + row) * 64 + cc] = vout[row * 65 + cc];
    }
}

// ---------------------------------------------------------------------------
// Merged pool layer: ONE launch; 4 atoms per block (one wave each, lane=ch).
// ---------------------------------------------------------------------------
template<int D>
__device__ __forceinline__ float pool_body(const float* __restrict__ z,
                                           const int* __restrict__ ad, int j, int c, float v)
{
    int idxs[D];
    #pragma unroll
    for (int n = 0; n < D; ++n) idxs[n] = ad[(size_t)j * D + n];
    #pragma unroll
    for (int n = 0; n < D; ++n) v = fmaxf(v, z[(size_t)idxs[n] * 64 + c]);
    return v;
}

__global__ __launch_bounds__(256) void pool_all_kernel(
    const float* __restrict__ z, AdjPtrs adj, float* __restrict__ p)
{
    int d = 0, rem = blockIdx.x;
    for (;;) { const int nb = (kCounts[d] + 3) >> 2; if (rem < nb) break; rem -= nb; ++d; }
    const int t = threadIdx.x;
    const int j = rem * 4 + (t >> 6);
    if (j >= kCounts[d]) return;
    const int c = t & 63;
    const int a = kStarts[d] + j;
    float v = z[(size_t)a * 64 + c];
    if (d > 0) {
        const int* __restrict__ ad = adj.p[d - 1];
        switch (d) {
        case 1:  v = pool_body<1 >(z, ad, j, c, v); break;
        case 2:  v = pool_body<2 >(z, ad, j, c, v); break;
        case 3:  v = pool_body<3 >(z, ad, j, c, v); break;
        case 4:  v = pool_body<4 >(z, ad, j, c, v); break;
        case 5:  v = pool_body<5 >(z, ad, j, c, v); break;
        case 6:  v = pool_body<6 >(z, ad, j, c, v); break;
        case 7:  v = pool_body<7 >(z, ad, j, c, v); break;
        case 8:  v = pool_body<8 >(z, ad, j, c, v); break;
        case 9:  v = pool_body<9 >(z, ad, j, c, v); break;
        default: v = pool_body<10>(z, ad, j, c, v); break;
        }
    }
    p[(size_t)a * 64 + c] = v;
}

// ---------------------------------------------------------------------------
// Counting sort by membership: hist -> scan -> scatter (+ per-position seg id).
// ---------------------------------------------------------------------------
__global__ __launch_bounds__(256) void hist_kernel(const int* __restrict__ mem,
                                                   int* __restrict__ cnt)
{
    const int a = blockIdx.x * 256 + threadIdx.x;
    if (a < NATOMS) atomicAdd(&cnt[mem[a]], 1);
}

__global__ __launch_bounds__(512) void scan_kernel(const int* __restrict__ cnt,
                                                   int* __restrict__ off,
                                                   int* __restrict__ cur)
{
    __shared__ int part[512];
    const int t = threadIdx.x;
    const int base = t * 64;
    int s = 0;
    #pragma unroll 8
    for (int i = 0; i < 64; ++i) s += cnt[base + i];
    part[t] = s;
    __syncthreads();
    for (int o = 1; o < 512; o <<= 1) {
        int v = (t >= o) ? part[t - o] : 0;
        __syncthreads();
        part[t] += v;
        __syncthreads();
    }
    int run = (t == 0) ? 0 : part[t - 1];
    for (int i = 0; i < 64; ++i) {
        off[base + i] = run;
        cur[base + i] = run;
        run += cnt[base + i];
    }
}

__global__ __launch_bounds__(256) void scatter_kernel(const int* __restrict__ mem,
                                                      int* __restrict__ cur,
                                                      int* __restrict__ sorted,
                                                      int* __restrict__ sid)
{
    const int a = blockIdx.x * 256 + threadIdx.x;
    if (a < NATOMS) {
        const int m = mem[a];
        const int pos = atomicAdd(&cur[m], 1);
        sorted[pos] = a;
        sid[pos] = m;
    }
}

__global__ void seg_init_kernel(float* __restrict__ segS, unsigned* __restrict__ segM)
{
    const int n = NBATCH * 128;
    for (int i = blockIdx.x * blockDim.x + threadIdx.x; i < n; i += gridDim.x * blockDim.x) {
        segS[i] = 0.f;
        segM[i] = 0x007FFFFFu; // enc(-inf)
    }
}

// ---------------------------------------------------------------------------
// Dense 64->128 + ReLU + BN2 over SORTED atoms (tiled GEMM, 64 rows x 128 ch
// per block) with fused segmented sum/max epilogue. LDS ~17KB -> 8 blocks/CU.
// ---------------------------------------------------------------------------
__global__ __launch_bounds__(256) void dense_seg_sorted_kernel(
    const float* __restrict__ p,
    const int* __restrict__ sorted, const int* __restrict__ sid,
    const float* __restrict__ Wd, const float* __restrict__ bd,
    const float* __restrict__ bng, const float* __restrict__ bnb,
    const float* __restrict__ bnm, const float* __restrict__ bnv,
    float* __restrict__ segS, unsigned* __restrict__ segM)
{
    __shared__ __align__(16) float s_p[64][64];   // staging; reused as v-buffer
    __shared__ int s_idx[64];
    __shared__ int s_sid[64];

    const int t = threadIdx.x;
    const int pos0 = blockIdx.x * 64;   // NATOMS = 15625 * 64 exactly

    if (t < 64) {
        s_idx[t] = sorted[pos0 + t];
        s_sid[t] = sid[pos0 + t];
    }
    __syncthreads();

    for (int v = t; v < 1024; v += 256) {
        const int row = v >> 4, k0 = (v & 15) * 4;
        const float4 r = *reinterpret_cast<const float4*>(p + (size_t)s_idx[row] * 64 + k0);
        s_p[k0 + 0][swzS64(row, k0 + 0)] = r.x;
        s_p[k0 + 1][swzS64(row, k0 + 1)] = r.y;
        s_p[k0 + 2][swzS64(row, k0 + 2)] = r.z;
        s_p[k0 + 3][swzS64(row, k0 + 3)] = r.w;
    }
    __syncthreads();

    const int ccol = (t & 31) * 4;   // 4 consecutive output channels
    const int rgrp = t >> 5;         // 8 rows: rgrp*8 .. rgrp*8+7

    float acc[8][4];
    #pragma unroll
    for (int i = 0; i < 8; ++i)
        #pragma unroll
        for (int j = 0; j < 4; ++j) acc[i][j] = 0.f;

    for (int k = 0; k < 64; ++k) {
        const float4 w = *reinterpret_cast<const float4*>(Wd + (size_t)k * 128 + ccol);
        const int sw = ((k >> 2) & 7) << 2;
        #pragma unroll
        for (int h = 0; h < 2; ++h) {
            const float4 rv = *reinterpret_cast<const float4*>(&s_p[k][(rgrp * 8 + h * 4) ^ sw]);
            const float rr[4] = {rv.x, rv.y, rv.z, rv.w};
            #pragma unroll
            for (int j = 0; j < 4; ++j) {
                acc[h*4+j][0] = fmaf(rr[j], w.x, acc[h*4+j][0]);
                acc[h*4+j][1] = fmaf(rr[j], w.y, acc[h*4+j][1]);
                acc[h*4+j][2] = fmaf(rr[j], w.z, acc[h*4+j][2]);
                acc[h*4+j][3] = fmaf(rr[j], w.w, acc[h*4+j][3]);
            }
        }
    }

    {
        const float4 bb = *reinterpret_cast<const float4*>(bd + ccol);
        const float4 gg = *reinterpret_cast<const float4*>(bng + ccol);
        const float4 be = *reinterpret_cast<const float4*>(bnb + ccol);
        const float4 mm = *reinterpret_cast<const float4*>(bnm + ccol);
        const float4 vv = *reinterpret_cast<const float4*>(bnv + ccol);
        const float bia[4] = {bb.x, bb.y, bb.z, bb.w};
        float sc[4], sh[4];
        sc[0] = rsqrtf(vv.x + 1e-3f) * gg.x; sh[0] = be.x - mm.x * sc[0];
        sc[1] = rsqrtf(vv.y + 1e-3f) * gg.y; sh[1] = be.y - mm.y * sc[1];
        sc[2] = rsqrtf(vv.z + 1e-3f) * gg.z; sh[2] = be.z - mm.z * sc[2];
        sc[3] = rsqrtf(vv.w + 1e-3f) * gg.w; sh[3] = be.w - mm.w * sc[3];
        #pragma unroll
        for (int i = 0; i < 8; ++i)
            #pragma unroll
            for (int j = 0; j < 4; ++j)
                acc[i][j] = fmaf(fmaxf(acc[i][j] + bia[j], 0.f), sc[j], sh[j]);
    }

    __syncthreads();   // all GEMM reads of s_p complete -> safe to overwrite

    float (*vbuf)[64] = s_p;
    const int halfSel = ccol >> 6;
    const int cc = ccol & 63;

    #pragma unroll
    for (int half = 0; half < 2; ++half) {
        if (halfSel == half) {
            #pragma unroll
            for (int i = 0; i < 8; ++i) {
                float4 o = make_float4(acc[i][0], acc[i][1], acc[i][2], acc[i][3]);
                *reinterpret_cast<float4*>(&vbuf[rgrp * 8 + i][cc]) = o;
            }
        }
        __syncthreads();

        const int c = t & 63;
        const int rbase = (t >> 6) * 16;
        const int gch = half * 64 + c;
        int cur = s_sid[rbase];
        float s = 0.f, mx = -INFINITY;
        for (int r = rbase; r < rbase + 16; ++r) {
            const int sd = s_sid[r];
            if (sd != cur) {
                atomicAdd(&segS[(size_t)cur * 128 + gch], s);
                atomicMax(&segM[(size_t)cur * 128 + gch], enc_f32(mx));
                cur = sd; s = 0.f; mx = -INFINITY;
            }
            const float v = vbuf[r][c];
            s += v;
            mx = fmaxf(mx, v);
        }
        atomicAdd(&segS[(size_t)cur * 128 + gch], s);
        atomicMax(&segM[(size_t)cur * 128 + gch], enc_f32(mx));
        __syncthreads();
    }
}

__global__ void nf_fin_kernel(const float* __restrict__ segS,
                              const unsigned* __restrict__ segM,
                              float* __restrict__ nf)
{
    const int i = blockIdx.x * blockDim.x + threadIdx.x; // < NBATCH*128
    const int m = i >> 7, c = i & 127;
    nf[(size_t)m * 256 + c]       = tanhf(segS[i]);
    nf[(size_t)m * 256 + 128 + c] = tanhf(dec_f32(segM[i]));
}

// fd0: h = relu(nf @ W + b), 32768x256 @ 256x256. 64x64 tile per block.
// 4x4 micro-tile compute.
__global__ __launch_bounds__(256) void fd0_kernel(
    const float* __restrict__ nf, const float* __restrict__ W, const float* __restrict__ b,
    float* __restrict__ h)
{
    __shared__ __align__(16) float sx[256][64];
    const int t = threadIdx.x;
    const int r0 = (blockIdx.x >> 2) * 64;
    const int c0 = (blockIdx.x & 3) * 64;
    for (int ch = 0; ch < 4; ++ch) {
        for (int v = t; v < 1024; v += 256) {
            const int row = v >> 4, k0 = (v & 15) * 4 + ch * 64;
            const float4 r = *reinterpret_cast<const float4*>(nf + (size_t)(r0 + row) * 256 + k0);
            sx[k0 + 0][swzS64(row, k0 + 0)] = r.x;
            sx[k0 + 1][swzS64(row, k0 + 1)] = r.y;
            sx[k0 + 2][swzS64(row, k0 + 2)] = r.z;
            sx[k0 + 3][swzS64(row, k0 + 3)] = r.w;
        }
    }
    __syncthreads();

    const int c4 = (t & 15) * 4;
    const int a4 = (t >> 4) * 4;

    float acc[4][4];
    #pragma unroll
    for (int i = 0; i < 4; ++i)
        #pragma unroll
        for (int j = 0; j < 4; ++j) acc[i][j] = 0.f;

    for (int k = 0; k < 256; ++k) {
        const int sw = ((k >> 2) & 7) << 2;
        const float4 sv = *reinterpret_cast<const float4*>(&sx[k][a4 ^ sw]);
        const float4 w = *reinterpret_cast<const float4*>(W + (size_t)k * 256 + c0 + c4);
        const float ss[4] = {sv.x, sv.y, sv.z, sv.w};
        #pragma unroll
        for (int i = 0; i < 4; ++i) {
            acc[i][0] = fmaf(ss[i], w.x, acc[i][0]);
            acc[i][1] = fmaf(ss[i], w.y, acc[i][1]);
            acc[i][2] = fmaf(ss[i], w.z, acc[i][2]);
            acc[i][3] = fmaf(ss[i], w.w, acc[i][3]);
        }
    }

    const float4 bb = *reinterpret_cast<const float4*>(b + c0 + c4);
    const float bi[4] = {bb.x, bb.y, bb.z, bb.w};
    #pragma unroll
    for (int i = 0; i < 4; ++i) {
        float4 o;
        o.x = fmaxf(acc[i][0] + bi[0], 0.f);
        o.y = fmaxf(acc[i][1] + bi[1], 0.f);
        o.z = fmaxf(acc[i][2] + bi[2], 0.f);
        o.w = fmaxf(acc[i][3] + bi[3], 0.f);
        *reinterpret_cast<float4*>(h + (size_t)(r0 + a4 + i) * 256 + c0 + c4) = o;
    }
}

// rd: logits = h @ W + b (256->24), then pairwise softmax.
__global__ __launch_bounds__(384) void rd_kernel(
    const float* __restrict__ h, const float* __restrict__ W, const float* __restrict__ b,
    float* __restrict__ outP, float* __restrict__ outL)
{
    __shared__ float sh[32][257];
    const int t = threadIdx.x;
    const int r0 = blockIdx.x * 32;
    for (int e = t; e < 32 * 256; e += 384) {
        const int ri = e >> 8, k = e & 255;
        sh[ri][k] = h[(size_t)(r0 + ri) * 256 + k];
    }
    __syncthreads();
    const int r = t / 12, pj = t % 12;
    float a0 = b[2 * pj], a1 = b[2 * pj + 1];
    for (int k = 0; k < 256; ++k) {
        const float hv = sh[r][k];
        a0 = fmaf(hv, W[k * 24 + 2 * pj],     a0);
        a1 = fmaf(hv, W[k * 24 + 2 * pj + 1], a1);
    }
    const size_t m = (size_t)(r0 + r);
    outL[m * 24 + 2 * pj]     = a0;
    outL[m * 24 + 2 * pj + 1] = a1;
    const float mx = fmaxf(a0, a1);
    const float e0 = expf(a0 - mx), e1 = expf(a1 - mx);
    const float inv = 1.f / (e0 + e1);
    outP[m * 24 + 2 * pj]     = e0 * inv;
    outP[m * 24 + 2 * pj + 1] = e1 * inv;
}

} // namespace

extern "C" void kernel_launch(void* const* d_in, const int* in_sizes, int n_in,
                              void* d_out, int out_size, void* d_ws, size_t ws_size,
                              hipStream_t stream)
{
    const float* x       = (const float*)d_in[0];
    const int*   mem     = (const int*)d_in[2];
    AdjPtrs adj;
    for (int d = 0; d < 10; ++d) adj.p[d] = (const int*)d_in[4 + d];
    const float* gc0_W = (const float*)d_in[14];
    const float* gc0_b = (const float*)d_in[15];
    const float* gc1_W = (const float*)d_in[16];
    const float* gc1_b = (const float*)d_in[17];
    const float* bn0g = (const float*)d_in[18], *bn0b = (const float*)d_in[19];
    const float* bn0m = (const float*)d_in[20], *bn0v = (const float*)d_in[21];
    const float* bn1g = (const float*)d_in[22], *bn1b = (const float*)d_in[23];
    const float* bn1m = (const float*)d_in[24], *bn1v = (const float*)d_in[25];
    const float* bn2g = (const float*)d_in[26], *bn2b = (const float*)d_in[27];
    const float* bn2m = (const float*)d_in[28], *bn2v = (const float*)d_in[29];
    const float* dW   = (const float*)d_in[30], *db   = (const float*)d_in[31];
    const float* fW   = (const float*)d_in[32], *fb   = (const float*)d_in[33];
    const float* rW   = (const float*)d_in[34], *rb   = (const float*)d_in[35];

    float*    zbuf = (float*)d_ws;
    float*    pbuf = zbuf + (size_t)NATOMS * 64;
    float*    hbuf = pbuf + (size_t)NATOMS * 64;
    float*    segS = hbuf + (size_t)NBATCH * 256;
    unsigned* segM = (unsigned*)(segS + (size_t)NBATCH * 128);
    int*      cnt    = (int*)(segM + (size_t)NBATCH * 128);
    int*      offp   = cnt + NBATCH;
    int*      cur    = offp + NBATCH;
    int*      sorted = cur + NBATCH;
    int*      sid    = sorted + NATOMS;

    float* outP = (float*)d_out;
    float* outL = outP + (size_t)NBATCH * 24;
    float* nfb  = outL + (size_t)NBATCH * 24;

    int convBlocks = 0, poolBlocks = 0;
    for (int d = 0; d <= 10; ++d) {
        convBlocks += (kCounts[d] + 63) >> 6;
        poolBlocks += (kCounts[d] + 3) >> 2;
    }

    // counting sort by membership + segment accumulator init
    hipMemsetAsync(cnt, 0, NBATCH * sizeof(int), stream);
    hist_kernel<<<(NATOMS + 255) / 256, 256, 0, stream>>>(mem, cnt);
    scan_kernel<<<1, 512, 0, stream>>>(cnt, offp, cur);
    scatter_kernel<<<(NATOMS + 255) / 256, 256, 0, stream>>>(mem, cur, sorted, sid);
    seg_init_kernel<<<2048, 256, 0, stream>>>(segS, segM);

    // layer 1: conv(75->64)+relu+bn0 -> pool   (one launch each)
    conv_all_kernel<75><<<convBlocks, 256, 0, stream>>>(x, adj, gc0_W, gc0_b,
                                                        bn0g, bn0b, bn0m, bn0v, zbuf);
    pool_all_kernel<<<poolBlocks, 256, 0, stream>>>(zbuf, adj, pbuf);

    // layer 2: conv(64->64)+relu+bn1 -> pool
    conv_all_kernel<64><<<convBlocks, 256, 0, stream>>>(pbuf, adj, gc1_W, gc1_b,
                                                        bn1g, bn1b, bn1m, bn1v, zbuf);
    pool_all_kernel<<<poolBlocks, 256, 0, stream>>>(zbuf, adj, pbuf);

    // dense+relu+bn2 over sorted atoms with fused segmented sum/max
    dense_seg_sorted_kernel<<<NATOMS / 64, 256, 0, stream>>>(
        pbuf, sorted, sid, dW, db, bn2g, bn2b, bn2m, bn2v, segS, segM);
    // nf = tanh(concat(sum, max))
    nf_fin_kernel<<<(NBATCH * 128) / 256, 256, 0, stream>>>(segS, segM, nfb);
    // h = relu(nf @ fd0_W + fd0_b)
    fd0_kernel<<<(NBATCH / 64) * 4, 256, 0, stream>>>(nfb, fW, fb, hbuf);
    // logits + softmax
    rd_kernel<<<NBATCH / 32, 384, 0, stream>>>(hbuf, rW, rb, outP, outL);
}

// Round 11
// 1886.513 us; speedup vs baseline: 1.2457x; 1.0113x over previous
//
#include <hip/hip_runtime.h>
#include <math.h>

namespace {

constexpr int NATOMS = 1000000;
constexpr int NBATCH = 32768;
constexpr int kCounts[11] = {10000,250000,300000,250000,120000,40000,15000,8000,4000,2000,1000};
constexpr int kStarts[11] = {0,10000,260000,560000,810000,930000,970000,985000,993000,997000,999000};

struct AdjPtrs { const int* p[10]; };

__device__ __forceinline__ unsigned enc_f32(float x) {
    unsigned u = __float_as_uint(x);
    return (u & 0x80000000u) ? ~u : (u | 0x80000000u);
}
__device__ __forceinline__ float dec_f32(unsigned u) {
    return (u & 0x80000000u) ? __uint_as_float(u & 0x7FFFFFFFu) : __uint_as_float(~u);
}

// Bank math (K-split conv): tiles [kl][64], row stride 64 = 0 mod 32 banks ->
// bank = col&31. Per-pattern swizzles, all <=2-way on staging writes and
// bijective in `a` for per-lane compute reads (2-way, free):
//  self64 (8 lanes/row float4):  col = row ^ ((kl>>2)<<2)     [kl<32]
//  self75 (16 lanes/row scalar): col = row ^ ((kl&7)<<2)
//  rel64  (4 lanes/atom float4): col = ai  ^ (((kl>>2)&3)<<3)
//  rel75  (4 lanes/atom scalar): col = ai  ^ ((kl&3)<<3)
__device__ __forceinline__ int swzS64(int row, int k) { return row ^ (((k >> 2) & 7) << 2); }

// ---------------------------------------------------------------------------
// K-split staging bodies (per phase: k in [k0, k0+len))
// ---------------------------------------------------------------------------
__device__ __forceinline__ void stage_self64_ph(const float* __restrict__ x,
                                                int a0, int nA, int t, int k0,
                                                float* __restrict__ s_self)
{
    for (int v = t; v < 512; v += 256) {
        const int row = v >> 3, q4 = v & 7;
        if (row < nA) {
            const float4 r = *reinterpret_cast<const float4*>(x + (size_t)(a0 + row) * 64 + k0 + q4 * 4);
            const int col = row ^ (q4 << 2);
            s_self[(q4 * 4 + 0) * 64 + col] = r.x;
            s_self[(q4 * 4 + 1) * 64 + col] = r.y;
            s_self[(q4 * 4 + 2) * 64 + col] = r.z;
            s_self[(q4 * 4 + 3) * 64 + col] = r.w;
        }
    }
}

__device__ __forceinline__ void stage_self75_ph(const float* __restrict__ x,
                                                int a0, int nA, int t, int k0, int len,
                                                float* __restrict__ s_self)
{
    for (int v = t; v < 1024; v += 256) {
        const int row = v >> 4, l16 = v & 15;
        if (row < nA) {
            const float* __restrict__ xr = x + (size_t)(a0 + row) * 75 + k0;
            #pragma unroll
            for (int q = 0; q < 3; ++q) {
                const int kl = l16 + 16 * q;
                if (kl < len) s_self[kl * 64 + (row ^ ((kl & 7) << 2))] = xr[kl];
            }
        }
    }
}

template<int D>
__device__ __forceinline__ void stage_rel64_ph(const float* __restrict__ x,
                                               const int* __restrict__ ad,
                                               int j0, int ai, int g4, int k0f4,
                                               float* __restrict__ s_rel)
{
    int idxs[D];
    #pragma unroll
    for (int n = 0; n < D; ++n) idxs[n] = ad[(size_t)(j0 + ai) * D + n];
    float4 r[2];
    r[0] = make_float4(0.f, 0.f, 0.f, 0.f);
    r[1] = make_float4(0.f, 0.f, 0.f, 0.f);
    for (int n = 0; n < D; ++n) {
        const float4* __restrict__ xr = reinterpret_cast<const float4*>(x + (size_t)idxs[n] * 64);
        #pragma unroll
        for (int q = 0; q < 2; ++q) {
            const float4 v = xr[k0f4 + g4 + 4 * q];
            r[q].x += v.x; r[q].y += v.y; r[q].z += v.z; r[q].w += v.w;
        }
    }
    const int col = ai ^ (g4 << 3);
    #pragma unroll
    for (int q = 0; q < 2; ++q) {
        const int klb = (g4 + 4 * q) * 4;
        s_rel[(klb + 0) * 64 + col] = r[q].x;
        s_rel[(klb + 1) * 64 + col] = r[q].y;
        s_rel[(klb + 2) * 64 + col] = r[q].z;
        s_rel[(klb + 3) * 64 + col] = r[q].w;
    }
}

__device__ __forceinline__ void stage_rel64_rt_ph(const float* __restrict__ x,
                                                  const int* __restrict__ ad, int d,
                                                  int j0, int ai, int g4, int k0f4,
                                                  float* __restrict__ s_rel)
{
    int idxs[10];
    for (int n = 0; n < d; ++n) idxs[n] = ad[(size_t)(j0 + ai) * d + n];
    float4 r[2];
    r[0] = make_float4(0.f, 0.f, 0.f, 0.f);
    r[1] = make_float4(0.f, 0.f, 0.f, 0.f);
    for (int n = 0; n < d; ++n) {
        const float4* __restrict__ xr = reinterpret_cast<const float4*>(x + (size_t)idxs[n] * 64);
        #pragma unroll
        for (int q = 0; q < 2; ++q) {
            const float4 v = xr[k0f4 + g4 + 4 * q];
            r[q].x += v.x; r[q].y += v.y; r[q].z += v.z; r[q].w += v.w;
        }
    }
    const int col = ai ^ (g4 << 3);
    #pragma unroll
    for (int q = 0; q < 2; ++q) {
        const int klb = (g4 + 4 * q) * 4;
        s_rel[(klb + 0) * 64 + col] = r[q].x;
        s_rel[(klb + 1) * 64 + col] = r[q].y;
        s_rel[(klb + 2) * 64 + col] = r[q].z;
        s_rel[(klb + 3) * 64 + col] = r[q].w;
    }
}

template<int D>
__device__ __forceinline__ void stage_rel75_ph(const float* __restrict__ x,
                                               const int* __restrict__ ad,
                                               int j0, int ai, int g4, int k0, int len,
                                               float* __restrict__ s_rel)
{
    int idxs[D];
    #pragma unroll
    for (int n = 0; n < D; ++n) idxs[n] = ad[(size_t)(j0 + ai) * D + n];
    float r[10];
    #pragma unroll
    for (int q = 0; q < 10; ++q) r[q] = 0.f;
    for (int n = 0; n < D; ++n) {
        const float* __restrict__ xr = x + (size_t)idxs[n] * 75 + k0;
        #pragma unroll
        for (int q = 0; q < 10; ++q) {
            const int e = g4 + 4 * q;
            if (e < len) r[q] += xr[e];
        }
    }
    #pragma unroll
    for (int q = 0; q < 10; ++q) {
        const int e = g4 + 4 * q;
        if (e < len) s_rel[e * 64 + (ai ^ (g4 << 3))] = r[q];
    }
}

__device__ __forceinline__ void stage_rel75_rt_ph(const float* __restrict__ x,
                                                  const int* __restrict__ ad, int d,
                                                  int j0, int ai, int g4, int k0, int len,
                                                  float* __restrict__ s_rel)
{
    int idxs[10];
    for (int n = 0; n < d; ++n) idxs[n] = ad[(size_t)(j0 + ai) * d + n];
    float r[10];
    #pragma unroll
    for (int q = 0; q < 10; ++q) r[q] = 0.f;
    for (int n = 0; n < d; ++n) {
        const float* __restrict__ xr = x + (size_t)idxs[n] * 75 + k0;
        #pragma unroll
        for (int q = 0; q < 10; ++q) {
            const int e = g4 + 4 * q;
            if (e < len) r[q] += xr[e];
        }
    }
    #pragma unroll
    for (int q = 0; q < 10; ++q) {
        const int e = g4 + 4 * q;
        if (e < len) s_rel[e * 64 + (ai ^ (g4 << 3))] = r[q];
    }
}

// ---------------------------------------------------------------------------
// compute phases (atom-per-lane, scalar weights)
// ---------------------------------------------------------------------------
template<int CI, int LEN>
__device__ __forceinline__ void compute_ph(const float* __restrict__ s_self,
                                           const float* __restrict__ s_rel,
                                           int a, int k0, int c0,
                                           const float* __restrict__ Ws,
                                           const float* __restrict__ Wr,
                                           float acc[16])
{
    #pragma unroll
    for (int kl = 0; kl < LEN; ++kl) {
        const int k = k0 + kl;
        const int colS = (CI == 64) ? (a ^ ((kl >> 2) << 2)) : (a ^ ((kl & 7) << 2));
        const int colR = (CI == 64) ? (a ^ (((kl >> 2) & 3) << 3)) : (a ^ ((kl & 3) << 3));
        const float xs = s_self[kl * 64 + colS];
        const float xr = s_rel [kl * 64 + colR];
        #pragma unroll
        for (int j = 0; j < 16; ++j)
            acc[j] = fmaf(xs, Ws[k * 64 + c0 + j],
                          fmaf(xr, Wr[k * 64 + c0 + j], acc[j]));
    }
}

template<int CI, int LEN>
__device__ __forceinline__ void compute_ph0(const float* __restrict__ s_self,
                                            int a, int k0, int c0,
                                            const float* __restrict__ Ws,
                                            float acc[16])
{
    #pragma unroll
    for (int kl = 0; kl < LEN; ++kl) {
        const int k = k0 + kl;
        const int colS = (CI == 64) ? (a ^ ((kl >> 2) << 2)) : (a ^ ((kl & 7) << 2));
        const float xs = s_self[kl * 64 + colS];
        #pragma unroll
        for (int j = 0; j < 16; ++j)
            acc[j] = fmaf(xs, Ws[k * 64 + c0 + j], acc[j]);
    }
}

// ---------------------------------------------------------------------------
// Merged conv layer, K-SPLIT: two stage+compute phases halve LDS (38.4->19.5KB)
// -> 8 blocks/CU = 32 waves/CU (was 16). Rounds 7-10 showed an ~285-330us
// stall invariant to compute formulation: the neighbor gather (40M independent
// 16B loads/layer at L3/HBM latency) is MLP-bound; doubling resident waves
// doubles outstanding loads. Per-phase gathers read DISJOINT row halves ->
// HBM traffic unchanged. Compute stays scalar-weight atom-per-lane (r10).
// ---------------------------------------------------------------------------
template<int CI>
__global__ __launch_bounds__(256) void conv_all_kernel(
    const float* __restrict__ x, AdjPtrs adj,
    const float* __restrict__ W, const float* __restrict__ B,
    const float* __restrict__ bng, const float* __restrict__ bnb,
    const float* __restrict__ bnm, const float* __restrict__ bnv,
    float* __restrict__ out)
{
    constexpr int KH = (CI + 1) / 2;               // 38 / 32
    constexpr int L0 = KH, L1 = CI - KH;           // 38,37 / 32,32
    constexpr int SM = (2 * KH * 64 > 64 * 65) ? 2 * KH * 64 : 64 * 65;
    __shared__ __align__(16) float smem[SM];
    float* s_self = smem;
    float* s_rel  = smem + KH * 64;

    int d = 0, rem = blockIdx.x;
    for (;;) { const int nb = (kCounts[d] + 63) >> 6; if (rem < nb) break; rem -= nb; ++d; }
    const int j0 = rem << 6;
    const int nA = min(64, kCounts[d] - j0);
    const int a0 = kStarts[d] + j0;
    const int t = threadIdx.x;
    const int a  = t & 63;
    const int c0 = __builtin_amdgcn_readfirstlane(t >> 6) * 16;   // wave-uniform

    const float* __restrict__ Ws0 = W + (size_t)(2 * 10) * CI * 64;
    const float* __restrict__ Wr  = (d > 0) ? W + (size_t)(2 * (d - 1)) * CI * 64 : nullptr;
    const float* __restrict__ Ws  = (d > 0) ? W + (size_t)(2 * d - 1) * CI * 64 : nullptr;
    const int* __restrict__ adp   = (d > 0) ? adj.p[d - 1] : nullptr;
    const int ai = t >> 2, g4 = t & 3;

    float acc[16];
    #pragma unroll
    for (int j = 0; j < 16; ++j) acc[j] = 0.f;

    // ================= phase 0: k in [0, L0) =================
    if constexpr (CI == 64) stage_self64_ph(x, a0, nA, t, 0, s_self);
    else                    stage_self75_ph(x, a0, nA, t, 0, L0, s_self);
    if (d > 0 && ai < nA) {
        if constexpr (CI == 64) {
            switch (d) {
            case 1: stage_rel64_ph<1>(x, adp, j0, ai, g4, 0, s_rel); break;
            case 2: stage_rel64_ph<2>(x, adp, j0, ai, g4, 0, s_rel); break;
            case 3: stage_rel64_ph<3>(x, adp, j0, ai, g4, 0, s_rel); break;
            case 4: stage_rel64_ph<4>(x, adp, j0, ai, g4, 0, s_rel); break;
            default: stage_rel64_rt_ph(x, adp, d, j0, ai, g4, 0, s_rel); break;
            }
        } else {
            switch (d) {
            case 1: stage_rel75_ph<1>(x, adp, j0, ai, g4, 0, L0, s_rel); break;
            case 2: stage_rel75_ph<2>(x, adp, j0, ai, g4, 0, L0, s_rel); break;
            case 3: stage_rel75_ph<3>(x, adp, j0, ai, g4, 0, L0, s_rel); break;
            case 4: stage_rel75_ph<4>(x, adp, j0, ai, g4, 0, L0, s_rel); break;
            default: stage_rel75_rt_ph(x, adp, d, j0, ai, g4, 0, L0, s_rel); break;
            }
        }
    }
    __syncthreads();
    if (d == 0) compute_ph0<CI, L0>(s_self, a, 0, c0, Ws0, acc);
    else        compute_ph <CI, L0>(s_self, s_rel, a, 0, c0, Ws, Wr, acc);
    __syncthreads();

    // ================= phase 1: k in [KH, CI) =================
    if constexpr (CI == 64) stage_self64_ph(x, a0, nA, t, KH, s_self);
    else                    stage_self75_ph(x, a0, nA, t, KH, L1, s_self);
    if (d > 0 && ai < nA) {
        if constexpr (CI == 64) {
            switch (d) {
            case 1: stage_rel64_ph<1>(x, adp, j0, ai, g4, KH / 4, s_rel); break;
            case 2: stage_rel64_ph<2>(x, adp, j0, ai, g4, KH / 4, s_rel); break;
            case 3: stage_rel64_ph<3>(x, adp, j0, ai, g4, KH / 4, s_rel); break;
            case 4: stage_rel64_ph<4>(x, adp, j0, ai, g4, KH / 4, s_rel); break;
            default: stage_rel64_rt_ph(x, adp, d, j0, ai, g4, KH / 4, s_rel); break;
            }
        } else {
            switch (d) {
            case 1: stage_rel75_ph<1>(x, adp, j0, ai, g4, KH, L1, s_rel); break;
            case 2: stage_rel75_ph<2>(x, adp, j0, ai, g4, KH, L1, s_rel); break;
            case 3: stage_rel75_ph<3>(x, adp, j0, ai, g4, KH, L1, s_rel); break;
            case 4: stage_rel75_ph<4>(x, adp, j0, ai, g4, KH, L1, s_rel); break;
            default: stage_rel75_rt_ph(x, adp, d, j0, ai, g4, KH, L1, s_rel); break;
            }
        }
    }
    __syncthreads();
    if (d == 0) compute_ph0<CI, L1>(s_self, a, KH, c0, Ws0, acc);
    else        compute_ph <CI, L1>(s_self, s_rel, a, KH, c0, Ws, Wr, acc);

    // ---- epilogue: scalar bias/BN, rotated-LDS transpose, coalesced store --
    __syncthreads();          // all LDS reads done -> safe to overwrite smem
    float* vout = smem;       // [64][65] rotated buffer
    #pragma unroll
    for (int j = 0; j < 16; ++j) {
        const int c = c0 + j;                               // wave-uniform
        const float bias = (d == 0) ? B[20 * 64 + c]
                                    : (B[(2 * (d - 1)) * 64 + c] + B[(2 * d - 1) * 64 + c]);
        const float scl = rsqrtf(bnv[c] + 1e-3f) * bng[c];
        const float sht = bnb[c] - bnm[c] * scl;
        vout[a * 65 + c] = fmaf(fmaxf(acc[j] + bias, 0.f), scl, sht);
    }
    __syncthreads();
    const int cc = t & 63, g = t >> 6;
    #pragma unroll
    for (int i = 0; i < 16; ++i) {
        const int row = g * 16 + i;
        if (row < nA) out[(size_t)(a0 + row) * 64 + cc] = vout[row * 65 + cc];
    }
}

// ---------------------------------------------------------------------------
// Merged pool layer: ONE launch; 4 atoms per block (one wave each, lane=ch).
// ---------------------------------------------------------------------------
template<int D>
__device__ __forceinline__ float pool_body(const float* __restrict__ z,
                                           const int* __restrict__ ad, int j, int c, float v)
{
    int idxs[D];
    #pragma unroll
    for (int n = 0; n < D; ++n) idxs[n] = ad[(size_t)j * D + n];
    #pragma unroll
    for (int n = 0; n < D; ++n) v = fmaxf(v, z[(size_t)idxs[n] * 64 + c]);
    return v;
}

__global__ __launch_bounds__(256) void pool_all_kernel(
    const float* __restrict__ z, AdjPtrs adj, float* __restrict__ p)
{
    int d = 0, rem = blockIdx.x;
    for (;;) { const int nb = (kCounts[d] + 3) >> 2; if (rem < nb) break; rem -= nb; ++d; }
    const int t = threadIdx.x;
    const int j = rem * 4 + (t >> 6);
    if (j >= kCounts[d]) return;
    const int c = t & 63;
    const int a = kStarts[d] + j;
    float v = z[(size_t)a * 64 + c];
    if (d > 0) {
        const int* __restrict__ ad = adj.p[d - 1];
        switch (d) {
        case 1:  v = pool_body<1 >(z, ad, j, c, v); break;
        case 2:  v = pool_body<2 >(z, ad, j, c, v); break;
        case 3:  v = pool_body<3 >(z, ad, j, c, v); break;
        case 4:  v = pool_body<4 >(z, ad, j, c, v); break;
        case 5:  v = pool_body<5 >(z, ad, j, c, v); break;
        case 6:  v = pool_body<6 >(z, ad, j, c, v); break;
        case 7:  v = pool_body<7 >(z, ad, j, c, v); break;
        case 8:  v = pool_body<8 >(z, ad, j, c, v); break;
        case 9:  v = pool_body<9 >(z, ad, j, c, v); break;
        default: v = pool_body<10>(z, ad, j, c, v); break;
        }
    }
    p[(size_t)a * 64 + c] = v;
}

// ---------------------------------------------------------------------------
// Counting sort by membership: hist -> scan -> scatter (+ per-position seg id).
// ---------------------------------------------------------------------------
__global__ __launch_bounds__(256) void hist_kernel(const int* __restrict__ mem,
                                                   int* __restrict__ cnt)
{
    const int a = blockIdx.x * 256 + threadIdx.x;
    if (a < NATOMS) atomicAdd(&cnt[mem[a]], 1);
}

__global__ __launch_bounds__(512) void scan_kernel(const int* __restrict__ cnt,
                                                   int* __restrict__ off,
                                                   int* __restrict__ cur)
{
    __shared__ int part[512];
    const int t = threadIdx.x;
    const int base = t * 64;
    int s = 0;
    #pragma unroll 8
    for (int i = 0; i < 64; ++i) s += cnt[base + i];
    part[t] = s;
    __syncthreads();
    for (int o = 1; o < 512; o <<= 1) {
        int v = (t >= o) ? part[t - o] : 0;
        __syncthreads();
        part[t] += v;
        __syncthreads();
    }
    int run = (t == 0) ? 0 : part[t - 1];
    for (int i = 0; i < 64; ++i) {
        off[base + i] = run;
        cur[base + i] = run;
        run += cnt[base + i];
    }
}

__global__ __launch_bounds__(256) void scatter_kernel(const int* __restrict__ mem,
                                                      int* __restrict__ cur,
                                                      int* __restrict__ sorted,
                                                      int* __restrict__ sid)
{
    const int a = blockIdx.x * 256 + threadIdx.x;
    if (a < NATOMS) {
        const int m = mem[a];
        const int pos = atomicAdd(&cur[m], 1);
        sorted[pos] = a;
        sid[pos] = m;
    }
}

__global__ void seg_init_kernel(float* __restrict__ segS, unsigned* __restrict__ segM)
{
    const int n = NBATCH * 128;
    for (int i = blockIdx.x * blockDim.x + threadIdx.x; i < n; i += gridDim.x * blockDim.x) {
        segS[i] = 0.f;
        segM[i] = 0x007FFFFFu; // enc(-inf)
    }
}

// ---------------------------------------------------------------------------
// Dense 64->128 + ReLU + BN2 over SORTED atoms (tiled GEMM, 64 rows x 128 ch
// per block) with fused segmented sum/max epilogue. LDS ~17KB -> 8 blocks/CU.
// ---------------------------------------------------------------------------
__global__ __launch_bounds__(256) void dense_seg_sorted_kernel(
    const float* __restrict__ p,
    const int* __restrict__ sorted, const int* __restrict__ sid,
    const float* __restrict__ Wd, const float* __restrict__ bd,
    const float* __restrict__ bng, const float* __restrict__ bnb,
    const float* __restrict__ bnm, const float* __restrict__ bnv,
    float* __restrict__ segS, unsigned* __restrict__ segM)
{
    __shared__ __align__(16) float s_p[64][64];   // staging; reused as v-buffer
    __shared__ int s_idx[64];
    __shared__ int s_sid[64];

    const int t = threadIdx.x;
    const int pos0 = blockIdx.x * 64;   // NATOMS = 15625 * 64 exactly

    if (t < 64) {
        s_idx[t] = sorted[pos0 + t];
        s_sid[t] = sid[pos0 + t];
    }
    __syncthreads();

    for (int v = t; v < 1024; v += 256) {
        const int row = v >> 4, k0 = (v & 15) * 4;
        const float4 r = *reinterpret_cast<const float4*>(p + (size_t)s_idx[row] * 64 + k0);
        s_p[k0 + 0][swzS64(row, k0 + 0)] = r.x;
        s_p[k0 + 1][swzS64(row, k0 + 1)] = r.y;
        s_p[k0 + 2][swzS64(row, k0 + 2)] = r.z;
        s_p[k0 + 3][swzS64(row, k0 + 3)] = r.w;
    }
    __syncthreads();

    const int ccol = (t & 31) * 4;   // 4 consecutive output channels
    const int rgrp = t >> 5;         // 8 rows: rgrp*8 .. rgrp*8+7

    float acc[8][4];
    #pragma unroll
    for (int i = 0; i < 8; ++i)
        #pragma unroll
        for (int j = 0; j < 4; ++j) acc[i][j] = 0.f;

    for (int k = 0; k < 64; ++k) {
        const float4 w = *reinterpret_cast<const float4*>(Wd + (size_t)k * 128 + ccol);
        const int sw = ((k >> 2) & 7) << 2;
        #pragma unroll
        for (int h = 0; h < 2; ++h) {
            const float4 rv = *reinterpret_cast<const float4*>(&s_p[k][(rgrp * 8 + h * 4) ^ sw]);
            const float rr[4] = {rv.x, rv.y, rv.z, rv.w};
            #pragma unroll
            for (int j = 0; j < 4; ++j) {
                acc[h*4+j][0] = fmaf(rr[j], w.x, acc[h*4+j][0]);
                acc[h*4+j][1] = fmaf(rr[j], w.y, acc[h*4+j][1]);
                acc[h*4+j][2] = fmaf(rr[j], w.z, acc[h*4+j][2]);
                acc[h*4+j][3] = fmaf(rr[j], w.w, acc[h*4+j][3]);
            }
        }
    }

    {
        const float4 bb = *reinterpret_cast<const float4*>(bd + ccol);
        const float4 gg = *reinterpret_cast<const float4*>(bng + ccol);
        const float4 be = *reinterpret_cast<const float4*>(bnb + ccol);
        const float4 mm = *reinterpret_cast<const float4*>(bnm + ccol);
        const float4 vv = *reinterpret_cast<const float4*>(bnv + ccol);
        const float bia[4] = {bb.x, bb.y, bb.z, bb.w};
        float sc[4], sh[4];
        sc[0] = rsqrtf(vv.x + 1e-3f) * gg.x; sh[0] = be.x - mm.x * sc[0];
        sc[1] = rsqrtf(vv.y + 1e-3f) * gg.y; sh[1] = be.y - mm.y * sc[1];
        sc[2] = rsqrtf(vv.z + 1e-3f) * gg.z; sh[2] = be.z - mm.z * sc[2];
        sc[3] = rsqrtf(vv.w + 1e-3f) * gg.w; sh[3] = be.w - mm.w * sc[3];
        #pragma unroll
        for (int i = 0; i < 8; ++i)
            #pragma unroll
            for (int j = 0; j < 4; ++j)
                acc[i][j] = fmaf(fmaxf(acc[i][j] + bia[j], 0.f), sc[j], sh[j]);
    }

    __syncthreads();   // all GEMM reads of s_p complete -> safe to overwrite

    float (*vbuf)[64] = s_p;
    const int halfSel = ccol >> 6;
    const int cc = ccol & 63;

    #pragma unroll
    for (int half = 0; half < 2; ++half) {
        if (halfSel == half) {
            #pragma unroll
            for (int i = 0; i < 8; ++i) {
                float4 o = make_float4(acc[i][0], acc[i][1], acc[i][2], acc[i][3]);
                *reinterpret_cast<float4*>(&vbuf[rgrp * 8 + i][cc]) = o;
            }
        }
        __syncthreads();

        const int c = t & 63;
        const int rbase = (t >> 6) * 16;
        const int gch = half * 64 + c;
        int cur = s_sid[rbase];
        float s = 0.f, mx = -INFINITY;
        for (int r = rbase; r < rbase + 16; ++r) {
            const int sd = s_sid[r];
            if (sd != cur) {
                atomicAdd(&segS[(size_t)cur * 128 + gch], s);
                atomicMax(&segM[(size_t)cur * 128 + gch], enc_f32(mx));
                cur = sd; s = 0.f; mx = -INFINITY;
            }
            const float v = vbuf[r][c];
            s += v;
            mx = fmaxf(mx, v);
        }
        atomicAdd(&segS[(size_t)cur * 128 + gch], s);
        atomicMax(&segM[(size_t)cur * 128 + gch], enc_f32(mx));
        __syncthreads();
    }
}

__global__ void nf_fin_kernel(const float* __restrict__ segS,
                              const unsigned* __restrict__ segM,
                              float* __restrict__ nf)
{
    const int i = blockIdx.x * blockDim.x + threadIdx.x; // < NBATCH*128
    const int m = i >> 7, c = i & 127;
    nf[(size_t)m * 256 + c]       = tanhf(segS[i]);
    nf[(size_t)m * 256 + 128 + c] = tanhf(dec_f32(segM[i]));
}

// fd0: h = relu(nf @ W + b), 32768x256 @ 256x256. 64x64 tile per block.
// 4x4 micro-tile compute.
__global__ __launch_bounds__(256) void fd0_kernel(
    const float* __restrict__ nf, const float* __restrict__ W, const float* __restrict__ b,
    float* __restrict__ h)
{
    __shared__ __align__(16) float sx[256][64];
    const int t = threadIdx.x;
    const int r0 = (blockIdx.x >> 2) * 64;
    const int c0 = (blockIdx.x & 3) * 64;
    for (int ch = 0; ch < 4; ++ch) {
        for (int v = t; v < 1024; v += 256) {
            const int row = v >> 4, k0 = (v & 15) * 4 + ch * 64;
            const float4 r = *reinterpret_cast<const float4*>(nf + (size_t)(r0 + row) * 256 + k0);
            sx[k0 + 0][swzS64(row, k0 + 0)] = r.x;
            sx[k0 + 1][swzS64(row, k0 + 1)] = r.y;
            sx[k0 + 2][swzS64(row, k0 + 2)] = r.z;
            sx[k0 + 3][swzS64(row, k0 + 3)] = r.w;
        }
    }
    __syncthreads();

    const int c4 = (t & 15) * 4;
    const int a4 = (t >> 4) * 4;

    float acc[4][4];
    #pragma unroll
    for (int i = 0; i < 4; ++i)
        #pragma unroll
        for (int j = 0; j < 4; ++j) acc[i][j] = 0.f;

    for (int k = 0; k < 256; ++k) {
        const int sw = ((k >> 2) & 7) << 2;
        const float4 sv = *reinterpret_cast<const float4*>(&sx[k][a4 ^ sw]);
        const float4 w = *reinterpret_cast<const float4*>(W + (size_t)k * 256 + c0 + c4);
        const float ss[4] = {sv.x, sv.y, sv.z, sv.w};
        #pragma unroll
        for (int i = 0; i < 4; ++i) {
            acc[i][0] = fmaf(ss[i], w.x, acc[i][0]);
            acc[i][1] = fmaf(ss[i], w.y, acc[i][1]);
            acc[i][2] = fmaf(ss[i], w.z, acc[i][2]);
            acc[i][3] = fmaf(ss[i], w.w, acc[i][3]);
        }
    }

    const float4 bb = *reinterpret_cast<const float4*>(b + c0 + c4);
    const float bi[4] = {bb.x, bb.y, bb.z, bb.w};
    #pragma unroll
    for (int i = 0; i < 4; ++i) {
        float4 o;
        o.x = fmaxf(acc[i][0] + bi[0], 0.f);
        o.y = fmaxf(acc[i][1] + bi[1], 0.f);
        o.z = fmaxf(acc[i][2] + bi[2], 0.f);
        o.w = fmaxf(acc[i][3] + bi[3], 0.f);
        *reinterpret_cast<float4*>(h + (size_t)(r0 + a4 + i) * 256 + c0 + c4) = o;
    }
}

// rd: logits = h @ W + b (256->24), then pairwise softmax.
__global__ __launch_bounds__(384) void rd_kernel(
    const float* __restrict__ h, const float* __restrict__ W, const float* __restrict__ b,
    float* __restrict__ outP, float* __restrict__ outL)
{
    __shared__ float sh[32][257];
    const int t = threadIdx.x;
    const int r0 = blockIdx.x * 32;
    for (int e = t; e < 32 * 256; e += 384) {
        const int ri = e >> 8, k = e & 255;
        sh[ri][k] = h[(size_t)(r0 + ri) * 256 + k];
    }
    __syncthreads();
    const int r = t / 12, pj = t % 12;
    float a0 = b[2 * pj], a1 = b[2 * pj + 1];
    for (int k = 0; k < 256; ++k) {
        const float hv = sh[r][k];
        a0 = fmaf(hv, W[k * 24 + 2 * pj],     a0);
        a1 = fmaf(hv, W[k * 24 + 2 * pj + 1], a1);
    }
    const size_t m = (size_t)(r0 + r);
    outL[m * 24 + 2 * pj]     = a0;
    outL[m * 24 + 2 * pj + 1] = a1;
    const float mx = fmaxf(a0, a1);
    const float e0 = expf(a0 - mx), e1 = expf(a1 - mx);
    const float inv = 1.f / (e0 + e1);
    outP[m * 24 + 2 * pj]     = e0 * inv;
    outP[m * 24 + 2 * pj + 1] = e1 * inv;
}

} // namespace

extern "C" void kernel_launch(void* const* d_in, const int* in_sizes, int n_in,
                              void* d_out, int out_size, void* d_ws, size_t ws_size,
                              hipStream_t stream)
{
    const float* x       = (const float*)d_in[0];
    const int*   mem     = (const int*)d_in[2];
    AdjPtrs adj;
    for (int d = 0; d < 10; ++d) adj.p[d] = (const int*)d_in[4 + d];
    const float* gc0_W = (const float*)d_in[14];
    const float* gc0_b = (const float*)d_in[15];
    const float* gc1_W = (const float*)d_in[16];
    const float* gc1_b = (const float*)d_in[17];
    const float* bn0g = (const float*)d_in[18], *bn0b = (const float*)d_in[19];
    const float* bn0m = (const float*)d_in[20], *bn0v = (const float*)d_in[21];
    const float* bn1g = (const float*)d_in[22], *bn1b = (const float*)d_in[23];
    const float* bn1m = (const float*)d_in[24], *bn1v = (const float*)d_in[25];
    const float* bn2g = (const float*)d_in[26], *bn2b = (const float*)d_in[27];
    const float* bn2m = (const float*)d_in[28], *bn2v = (const float*)d_in[29];
    const float* dW   = (const float*)d_in[30], *db   = (const float*)d_in[31];
    const float* fW   = (const float*)d_in[32], *fb   = (const float*)d_in[33];
    const float* rW   = (const float*)d_in[34], *rb   = (const float*)d_in[35];

    float*    zbuf = (float*)d_ws;
    float*    pbuf = zbuf + (size_t)NATOMS * 64;
    float*    hbuf = pbuf + (size_t)NATOMS * 64;
    float*    segS = hbuf + (size_t)NBATCH * 256;
    unsigned* segM = (unsigned*)(segS + (size_t)NBATCH * 128);
    int*      cnt    = (int*)(segM + (size_t)NBATCH * 128);
    int*      offp   = cnt + NBATCH;
    int*      cur    = offp + NBATCH;
    int*      sorted = cur + NBATCH;
    int*      sid    = sorted + NATOMS;

    float* outP = (float*)d_out;
    float* outL = outP + (size_t)NBATCH * 24;
    float* nfb  = outL + (size_t)NBATCH * 24;

    int convBlocks = 0, poolBlocks = 0;
    for (int d = 0; d <= 10; ++d) {
        convBlocks += (kCounts[d] + 63) >> 6;
        poolBlocks += (kCounts[d] + 3) >> 2;
    }

    // counting sort by membership + segment accumulator init
    hipMemsetAsync(cnt, 0, NBATCH * sizeof(int), stream);
    hist_kernel<<<(NATOMS + 255) / 256, 256, 0, stream>>>(mem, cnt);
    scan_kernel<<<1, 512, 0, stream>>>(cnt, offp, cur);
    scatter_kernel<<<(NATOMS + 255) / 256, 256, 0, stream>>>(mem, cur, sorted, sid);
    seg_init_kernel<<<2048, 256, 0, stream>>>(segS, segM);

    // layer 1: conv(75->64)+relu+bn0 -> pool   (one launch each)
    conv_all_kernel<75><<<convBlocks, 256, 0, stream>>>(x, adj, gc0_W, gc0_b,
                                                        bn0g, bn0b, bn0m, bn0v, zbuf);
    pool_all_kernel<<<poolBlocks, 256, 0, stream>>>(zbuf, adj, pbuf);

    // layer 2: conv(64->64)+relu+bn1 -> pool
    conv_all_kernel<64><<<convBlocks, 256, 0, stream>>>(pbuf, adj, gc1_W, gc1_b,
                                                        bn1g, bn1b, bn1m, bn1v, zbuf);
    pool_all_kernel<<<poolBlocks, 256, 0, stream>>>(zbuf, adj, pbuf);

    // dense+relu+bn2 over sorted atoms with fused segmented sum/max
    dense_seg_sorted_kernel<<<NATOMS / 64, 256, 0, stream>>>(
        pbuf, sorted, sid, dW, db, bn2g, bn2b, bn2m, bn2v, segS, segM);
    // nf = tanh(concat(sum, max))
    nf_fin_kernel<<<(NBATCH * 128) / 256, 256, 0, stream>>>(segS, segM, nfb);
    // h = relu(nf @ fd0_W + fd0_b)
    fd0_kernel<<<(NBATCH / 64) * 4, 256, 0, stream>>>(nfb, fW, fb, hbuf);
    // logits + softmax
    rd_kernel<<<NBATCH / 32, 384, 0, stream>>>(hbuf, rW, rb, outP, outL);
}